// Round 9
// baseline (443.252 us; speedup 1.0000x reference)
//
#include <hip/hip_runtime.h>
#include <hip/hip_bf16.h>
#include <stdint.h>

#define B_ 8
#define L_ 1024
#define H_ 768
#define E_ 16
#define W_ 504
#define DFF_ 512
#define N_ 5982
#define NE_ (N_*E_)    // 95712 candidates per batch
#define BNE_ (B_*NE_)  // 765696
#define MAXC_ 6144
#define MAXK48 0x0000FFFFFFFFFFFFull
#define PT_ 24         // per-thread elements in k_tailA (24*256 = 6144 >= N_)

typedef unsigned long long u64;
typedef unsigned int u32;

__device__ __forceinline__ int rowstart_of(int s){
    int s0 = W_ - 11; // 493
    if (s <= s0) return 12*s;
    int t = s - s0;
    return 12*s0 + t*11 - (t*(t-1))/2;
}

__device__ __forceinline__ u64 shflup_u64(u64 x, int d){
    u32 lo = (u32)__shfl_up((int)(u32)x, d, 64);
    u32 hi = (u32)__shfl_up((int)(u32)(x >> 32), d, 64);
    return ((u64)hi << 32) | (u64)lo;
}
__device__ __forceinline__ u64 shflxor_u64(u64 x, int m){
    u32 lo = (u32)__shfl_xor((int)(u32)x, m, 64);
    u32 hi = (u32)__shfl_xor((int)(u32)(x >> 32), m, 64);
    return ((u64)hi << 32) | (u64)lo;
}

// ---------------- prolog: span tables + tokc zero (block 8), parallel entpos (blocks 0..7) ----
__global__ void k_prolog(const int* __restrict__ ent_mask, int* __restrict__ ent_pos,
                         int* __restrict__ starts, int* __restrict__ ends,
                         int* __restrict__ tokc){
    int blk = blockIdx.x; int tid = threadIdx.x;
    if (blk == 8){
        for (int s = tid; s < W_; s += 256){
            int rs = rowstart_of(s);
            int cnt = min(12, W_ - s);
            for (int i = 0; i < cnt; i++){ starts[rs+i] = s; ends[rs+i] = s+i; }
        }
        for (int i = tid; i < B_*W_; i += 256) tokc[i] = 0;
        return;
    }
    __shared__ u32 wt[4]; __shared__ u32 cbase;
    int b = blk;
    int lane = tid & 63, wave = tid >> 6;
    if (tid == 0) cbase = 0;
    __syncthreads();
    for (int base = 0; base < L_; base += 256){
        int l = base + tid;
        bool f = (ent_mask[b*L_ + l] == 1);
        u64 bal = __ballot(f);
        if (lane == 0) wt[wave] = (u32)__popcll(bal);
        __syncthreads();
        u32 pre = cbase;
        for (int w = 0; w < 4; w++) if (w < wave) pre += wt[w];
        if (f){
            u32 rank = pre + (u32)__popcll(bal & ((1ull<<lane)-1ull));
            if (rank < E_) ent_pos[b*E_ + rank] = l;
        }
        __syncthreads();
        if (tid == 0){ u32 r = cbase; for (int w = 0; w < 4; w++) r += wt[w]; cbase = r; }
        __syncthreads();
    }
    u32 totEnt = cbase;
    if (totEnt >= E_) return;                 // block-uniform
    for (int base = 0; base < L_; base += 256){
        int l = base + tid;
        bool f = (ent_mask[b*L_ + l] != 1);
        u64 bal = __ballot(f);
        if (lane == 0) wt[wave] = (u32)__popcll(bal);
        __syncthreads();
        u32 pre = cbase;
        for (int w = 0; w < 4; w++) if (w < wave) pre += wt[w];
        if (f){
            u32 rank = pre + (u32)__popcll(bal & ((1ull<<lane)-1ull));
            if (rank < E_) ent_pos[b*E_ + rank] = l;
        }
        __syncthreads();
        if (tid == 0){ u32 r = cbase; for (int w = 0; w < 4; w++) r += wt[w]; cbase = r; }
        __syncthreads();
    }
}

// ---------------- token lists: parallel build ----------------
__global__ void k_toklist(const int* __restrict__ tm, const int* __restrict__ wi,
                          int* __restrict__ tok, int* __restrict__ tokc){
    int i = blockIdx.x*256 + threadIdx.x;
    if (i >= B_*L_) return;
    int w = wi[i];
    if (tm[i] == 1 && w >= 0 && w < W_){
        int b = i / L_;
        int bw = b*W_ + w;
        int pos = atomicAdd(&tokc[bw], 1);
        if (pos < 4) tok[bw*4 + pos] = i - b*L_;
    }
}

// ---------------- fused per-word sort + mean pooling (one block per (b,w)) ----------------
__global__ void k_poolsort(const float* __restrict__ hs, const int* __restrict__ tok,
                           const int* __restrict__ tokc, float* __restrict__ wemb){
    __shared__ int stok[4]; __shared__ int scnt;
    int bw = blockIdx.x;                       // B_*W_
    int b = bw / W_;
    int tid = threadIdx.x;
    if (tid == 0){
        int c = tokc[bw]; int cc = min(c, 4);
        int v[4];
        for (int k = 0; k < cc; k++) v[k] = tok[bw*4 + k];
        for (int a = 1; a < cc; a++){ int x = v[a]; int j = a-1; while (j >= 0 && v[j] > x){ v[j+1] = v[j]; j--; } v[j+1] = x; }
        for (int k = 0; k < cc; k++) stok[k] = v[k];
        scnt = c;
    }
    __syncthreads();
    int c = scnt; int cc = min(c, 4);
    float denom = (float)max(c, 1);
    for (int h = tid; h < H_; h += 256){
        double s = 0.0;
        for (int k = 0; k < cc; k++)
            s += (double)hs[((size_t)(b*L_ + stok[k]))*H_ + h];
        wemb[(size_t)bw*H_ + h] = (float)(s / (double)denom);
    }
}

// ---------------- entity MLP layer 1 (one output/thread; deep load pipeline) ----------------
__global__ void k_ent1(const float* __restrict__ hs, const int* __restrict__ ent_pos,
                       const float* __restrict__ w1, const float* __restrict__ b1,
                       float* __restrict__ hidg){
    __shared__ float x[H_];
    int blk = blockIdx.x;            // 256 blocks: be*2 + half
    int be = blk >> 1; int half = blk & 1;
    int b = be >> 4;
    int tid = threadIdx.x;
    int pos = ent_pos[be];
    const float* xp = hs + ((size_t)b*L_ + pos)*H_;
    for (int j = tid; j < H_; j += 256) x[j] = xp[j];
    __syncthreads();
    int d = half*256 + tid;
    float a0=0.f,a1=0.f,a2=0.f,a3=0.f;
    const float* wp = w1 + d;
    #pragma unroll 8
    for (int h = 0; h < H_; h += 4){
        a0 += x[h+0]*wp[(size_t)(h+0)*DFF_];
        a1 += x[h+1]*wp[(size_t)(h+1)*DFF_];
        a2 += x[h+2]*wp[(size_t)(h+2)*DFF_];
        a3 += x[h+3]*wp[(size_t)(h+3)*DFF_];
    }
    float acc = ((a0+a1)+(a2+a3)) + b1[d];
    hidg[(size_t)be*DFF_ + d] = acc > 0.f ? acc : 0.01f*acc;
}

// ---------------- entity MLP layer 2 (one output/thread; deep load pipeline) ----------------
__global__ void k_ent2(const float* __restrict__ hidg,
                       const float* __restrict__ w2, const float* __restrict__ b2,
                       float* __restrict__ ent_vec){
    __shared__ float hsd[DFF_];
    int blk = blockIdx.x;            // 384 blocks: be*3 + third
    int be = blk / 3; int third = blk % 3;
    int tid = threadIdx.x;
    const float* hp = hidg + (size_t)be*DFF_;
    for (int j = tid; j < DFF_; j += 256) hsd[j] = hp[j];
    __syncthreads();
    int j = third*256 + tid;
    float a0=0.f,a1=0.f,a2=0.f,a3=0.f;
    const float* wp = w2 + j;
    #pragma unroll 8
    for (int d = 0; d < DFF_; d += 4){
        a0 += hsd[d+0]*wp[(size_t)(d+0)*H_];
        a1 += hsd[d+1]*wp[(size_t)(d+1)*H_];
        a2 += hsd[d+2]*wp[(size_t)(d+2)*H_];
        a3 += hsd[d+3]*wp[(size_t)(d+3)*H_];
    }
    ent_vec[(size_t)be*H_ + j] = ((a0+a1)+(a2+a3)) + b2[j];
}

// ---------------- fused M + c: blocks 0..255 = M, block 256 = c (fp64, decode-critical) ------
__global__ void k_Mc(const float* __restrict__ span_w2, const float* __restrict__ span_b2,
                     const float* __restrict__ ent_vec, float* __restrict__ M,
                     float* __restrict__ cvec){
    int blk = blockIdx.x;
    if (blk == 256){
        int i = threadIdx.x;
        if (i < B_*E_){
            const float* ev = ent_vec + (size_t)i*H_;
            double acc = 0.0;
            for (int h = 0; h < H_; h++) acc += (double)span_b2[h]*(double)ev[h];
            cvec[i] = (float)acc;
        }
        return;
    }
    int b = blk/32; int dbase = (blk%32)*16;
    int tid = threadIdx.x; int d = dbase + (tid>>4); int e = tid&15;
    const float* ev = ent_vec + ((size_t)b*E_ + e)*H_;
    const float* wr = span_w2 + (size_t)d*H_;
    double p0=0.0, p1=0.0;
    for (int h = 0; h < H_; h += 2){
        p0 += (double)wr[h]*(double)ev[h];
        p1 += (double)wr[h+1]*(double)ev[h+1];
    }
    M[((size_t)b*DFF_ + d)*E_ + e] = (float)(p0+p1);
}

// ---------------- P/Q projection: tiled fp32 GEMM, 64x64 tiles, 4 batches per pass ----------
__global__ void k_pq(const float* __restrict__ wemb, const float* __restrict__ w1,
                     float* __restrict__ PQ, int b0){
    __shared__ float As[16][68];
    __shared__ float Bs[16][68];
    int bx = blockIdx.x & 15;      // col tile
    int by = blockIdx.x >> 4;      // row tile (0..31)
    int tid = threadIdx.x;
    int tm = tid >> 4, tn = tid & 15;
    const float* A0 = wemb + (size_t)b0*W_*H_;
    int colbase = bx*64;
    const float* Bbase = (colbase < DFF_) ? w1 : (w1 + (size_t)H_*DFF_);
    int bcol0 = (colbase < DFF_) ? colbase : (colbase - DFF_);
    float acc[4][4] = {{0.f}};
    int ar = tid >> 2, akq = tid & 3;
    int bkk = tid >> 4, bcq = tid & 15;
    const int ROWS = 4*W_;         // 2016
    for (int k0 = 0; k0 < H_; k0 += 16){
        {
            int gr = by*64 + ar;
            float4 av;
            if (gr < ROWS) av = *(const float4*)(A0 + (size_t)gr*H_ + k0 + akq*4);
            else av = make_float4(0.f,0.f,0.f,0.f);
            As[akq*4+0][ar] = av.x; As[akq*4+1][ar] = av.y;
            As[akq*4+2][ar] = av.z; As[akq*4+3][ar] = av.w;
        }
        {
            float4 bv = *(const float4*)(Bbase + (size_t)(k0+bkk)*DFF_ + bcol0 + bcq*4);
            Bs[bkk][bcq*4+0] = bv.x; Bs[bkk][bcq*4+1] = bv.y;
            Bs[bkk][bcq*4+2] = bv.z; Bs[bkk][bcq*4+3] = bv.w;
        }
        __syncthreads();
        #pragma unroll
        for (int kk = 0; kk < 16; kk++){
            float4 a = *(const float4*)&As[kk][tm*4];
            float4 bv = *(const float4*)&Bs[kk][tn*4];
            acc[0][0] += a.x*bv.x; acc[0][1] += a.x*bv.y; acc[0][2] += a.x*bv.z; acc[0][3] += a.x*bv.w;
            acc[1][0] += a.y*bv.x; acc[1][1] += a.y*bv.y; acc[1][2] += a.y*bv.z; acc[1][3] += a.y*bv.w;
            acc[2][0] += a.z*bv.x; acc[2][1] += a.z*bv.y; acc[2][2] += a.z*bv.z; acc[2][3] += a.z*bv.w;
            acc[3][0] += a.w*bv.x; acc[3][1] += a.w*bv.y; acc[3][2] += a.w*bv.z; acc[3][3] += a.w*bv.w;
        }
        __syncthreads();
    }
    #pragma unroll
    for (int r = 0; r < 4; r++){
        int gr = by*64 + tm*4 + r;
        if (gr < ROWS){
            float4 ov = make_float4(acc[r][0], acc[r][1], acc[r][2], acc[r][3]);
            *(float4*)(PQ + (size_t)gr*1024 + colbase + tn*4) = ov;
        }
    }
}

// ---------------- logits: one block per (bl, s); 4-way fp64 accum + wave-shuffle reduce ------
__global__ void k_logits(const float* __restrict__ PQ, const float* __restrict__ Mmat,
                         const float* __restrict__ cvec, const float* __restrict__ span_b1,
                         float* __restrict__ logits, float* __restrict__ outL, int b0){
    __shared__ float Ps[DFF_];
    __shared__ float hid[DFF_];
    __shared__ double redw[64];
    __shared__ float csh[E_];
    int blk = blockIdx.x;            // 4*W_ blocks
    int bl = blk / W_; int s = blk - bl*W_;
    int b = b0 + bl;
    int tid = threadIdx.x;
    int lane = tid & 63, wave = tid >> 6;
    int ee = tid & 15; int g = tid >> 4;   // 16 groups x 32 d
    float Mreg[32];
    {
        const float* Mp = Mmat + (size_t)b*DFF_*E_ + (size_t)(g*32)*E_ + ee;
        #pragma unroll
        for (int i = 0; i < 32; i++) Mreg[i] = Mp[(size_t)i*E_];
    }
    const float* P = PQ + ((size_t)(bl*W_ + s))*1024;
    for (int d = tid; d < DFF_; d += 256) Ps[d] = P[d] + span_b1[d];
    if (tid < E_) csh[tid] = cvec[b*E_ + tid];
    __syncthreads();
    int nsp = min(12, W_ - s);
    int nbase = rowstart_of(s);
    for (int i = 0; i < nsp; i++){
        int e = s + i;
        const float* Q = PQ + ((size_t)(bl*W_ + e))*1024 + DFF_;
        for (int d = tid; d < DFF_; d += 256){
            float h = Ps[d] + Q[d];
            hid[d] = h > 0.f ? h : 0.01f*h;
        }
        __syncthreads();
        {
            int d0 = g*32;
            double a0=0.0, a1=0.0, a2=0.0, a3=0.0;   // 4 chains break the serial FMA dep
            #pragma unroll
            for (int k = 0; k < 32; k += 4){
                a0 += (double)hid[d0+k+0]*(double)Mreg[k+0];
                a1 += (double)hid[d0+k+1]*(double)Mreg[k+1];
                a2 += (double)hid[d0+k+2]*(double)Mreg[k+2];
                a3 += (double)hid[d0+k+3]*(double)Mreg[k+3];
            }
            double acc = (a0+a1)+(a2+a3);
            double t = acc + __shfl_down(acc, 32, 64);
            t = t + __shfl_down(t, 16, 64);
            if (lane < 16) redw[wave*16 + lane] = t;
        }
        __syncthreads();
        if (tid < E_){
            double t = ((redw[tid] + redw[16+tid]) + (redw[32+tid] + redw[48+tid]))
                     + (double)csh[tid];
            float lg = (float)t;
            size_t oi = ((size_t)b*N_ + nbase + i)*E_ + tid;
            logits[oi] = lg;
            outL[oi] = lg;
        }
        __syncthreads();
    }
}

// ---------------- per-span best candidate + selected-region zeroing ----------------
__global__ void k_spanbest(const float* __restrict__ logits,
                           const int* __restrict__ starts, const int* __restrict__ ends,
                           u64* __restrict__ candS, float* __restrict__ outSel){
    int idx = blockIdx.x*256 + threadIdx.x;      // over B_*N_
    if (idx >= B_*N_) return;
    int b = idx / N_; int n = idx - b*N_;
    const float* lg = logits + (size_t)b*NE_ + (size_t)n*16;
    u64 best = ~0ull;
    for (int e = 0; e < 16; e++){
        float prob = 1.0f/(1.0f + expf(-lg[e]));
        if (prob > 0.5f){
            u32 key24 = (~__float_as_uint(prob)) & 0xFFFFFFu;
            u64 pk = ((u64)key24 << 24) | (u64)(u32)(n*16 + e);
            best = best < pk ? best : pk;
        }
    }
    int s = starts[n], e2 = ends[n];
    int len = e2 - s + 1;
    u64 packed = best;
    if (best != ~0ull)
        packed = best | ((u64)(u32)s << 48) | ((u64)(u32)(len-1) << 57);
    candS[idx] = packed;
    float* selp = outSel + (size_t)BNE_ + (size_t)b*NE_ + (size_t)n*16;
    float4 z = make_float4(0.f,0.f,0.f,0.f);
    *(float4*)(selp+0)  = z; *(float4*)(selp+4)  = z;
    *(float4*)(selp+8)  = z; *(float4*)(selp+12) = z;
}

// ---------------- greedy decode: wave-parallel prefix-OR rounds + serial pending -------------
__device__ __forceinline__ void decode_wave(const u64* sp, int n,
                                            float* __restrict__ outSel, int b){
    int lane = threadIdx.x & 63;
    u64 scov[8];
    #pragma unroll
    for (int k = 0; k < 8; k++) scov[k] = 0ull;
    int covcnt = 0;
    for (int base = 0; base < n; base += 64){
        int i = base + lane;
        bool has = i < n;
        u64 v = has ? sp[i] : ~0ull;
        int s   = (int)((v >> 48) & 0x1FFull);
        int len = (int)((v >> 57) & 0xFull) + 1;
        u32 c   = (u32)(v & 0xFFFFFFull);
        int w0 = s >> 6, sh0 = s & 63;
        int w1i = (w0 < 7) ? w0 + 1 : 7;
        u64 full = (1ull << len) - 1ull;
        u64 m0 = has ? (full << sh0) : 0ull;
        u64 m1 = (has && sh0 + len > 64) ? (full >> (64 - sh0)) : 0ull;
        u64 myc0 = 0ull, myc1 = 0ull;
        #pragma unroll
        for (int k = 0; k < 8; k++){
            if (w0  == k) myc0 = scov[k];
            if (w1i == k) myc1 = scov[k];
        }
        bool alive = has && (((myc0 & m0) | (myc1 & m1)) == 0ull);
        bool accept = false;
        u64 balv = __ballot(alive);
        if (balv){
            u64 pm[8];
            #pragma unroll
            for (int k = 0; k < 8; k++){
                u64 t = 0ull;
                if (alive){
                    if (w0  == k) t |= m0;
                    if (w1i == k) t |= m1;
                }
                pm[k] = t;
            }
            #pragma unroll
            for (int st = 1; st < 64; st <<= 1){
                #pragma unroll
                for (int k = 0; k < 8; k++) pm[k] |= shflup_u64(pm[k], st);
            }
            u64 ex0 = 0ull, ex1 = 0ull;
            #pragma unroll
            for (int k = 0; k < 8; k++){
                u64 e = shflup_u64(pm[k], 1);
                e = (lane == 0) ? 0ull : e;
                if (w0  == k) ex0 = e;
                if (w1i == k) ex1 = e;
            }
            bool blocked = (((ex0 & m0) | (ex1 & m1)) != 0ull);
            bool newacc = alive && !blocked;
            accept = newacc;
            u64 am[8];
            #pragma unroll
            for (int k = 0; k < 8; k++){
                u64 t = 0ull;
                if (newacc){
                    if (w0  == k) t |= m0;
                    if (w1i == k) t |= m1;
                }
                am[k] = t;
            }
            #pragma unroll
            for (int st = 1; st < 64; st <<= 1){
                #pragma unroll
                for (int k = 0; k < 8; k++) am[k] |= shflxor_u64(am[k], st);
            }
            #pragma unroll
            for (int k = 0; k < 8; k++){
                covcnt += (int)__popcll(am[k]);
                scov[k] |= am[k];
            }
            u64 pend = __ballot(alive && blocked);
            u32 vlo = (u32)v, vhi = (u32)(v >> 32);
            u64 accm = 0ull;
            while (pend){
                int j = (int)__builtin_ctzll(pend);
                pend &= pend - 1ull;
#if __has_builtin(__builtin_amdgcn_readlane)
                u32 jlo = (u32)__builtin_amdgcn_readlane((int)vlo, j);
                u32 jhi = (u32)__builtin_amdgcn_readlane((int)vhi, j);
#else
                u32 jlo = (u32)__shfl((int)vlo, j, 64);
                u32 jhi = (u32)__shfl((int)vhi, j, 64);
#endif
                u64 jv = ((u64)jhi << 32) | (u64)jlo;
                int js   = (int)((jv >> 48) & 0x1FFull);
                int jlen = (int)((jv >> 57) & 0xFull) + 1;
                int jw0 = js >> 6, jsh = js & 63;
                int jw1 = (jw0 < 7) ? jw0 + 1 : 7;
                u64 jfull = (1ull << jlen) - 1ull;
                u64 jm0 = jfull << jsh;
                u64 jm1 = (jsh + jlen > 64) ? (jfull >> (64 - jsh)) : 0ull;
                u64 c0 = 0ull, c1 = 0ull;
                #pragma unroll
                for (int k = 0; k < 8; k++){
                    if (jw0 == k) c0 = scov[k];
                    if (jw1 == k) c1 = scov[k];
                }
                bool ok = (((c0 & jm0) | (c1 & jm1)) == 0ull);
                u64 okm = ok ? ~0ull : 0ull;
                #pragma unroll
                for (int k = 0; k < 8; k++){
                    u64 add = 0ull;
                    if (jw0 == k) add |= jm0;
                    if (jw1 == k) add |= jm1;
                    scov[k] |= (add & okm);
                }
                covcnt += ok ? jlen : 0;
                accm |= (okm & (1ull << j));
            }
            if (((accm >> lane) & 1ull) != 0ull) accept = true;
        }
        if (accept)
            outSel[(size_t)BNE_ + (size_t)b*NE_ + (size_t)c] = 1.0f;
        if (covcnt >= W_) break;
    }
}

// ---------------- tail A: load -> DP -> compact -> rank-sort -> write sorted (256 thr) -------
__global__ __launch_bounds__(256) void k_tailA(const u64* __restrict__ candS,
                                               u64* __restrict__ candO, int* __restrict__ cntp){
    __shared__ u64 cs[6032];          // candidate table, then compacted+sorted (+pad 16)
    __shared__ u64 Ma[512], Mb[512];  // DP ping-pong
    __shared__ u32 wtot[4];
    __shared__ int nsh;
    int b = blockIdx.x; int tid = threadIdx.x;
    int lane = tid & 63, wave = tid >> 6;
    const u64* cSg = candS + (size_t)b*N_;

    // ---- load table -> LDS (fully unrolled: 24 independent loads in flight) ----
    #pragma unroll
    for (int k = 0; k < 23; k++) cs[tid + k*256] = cSg[tid + k*256];
    { int i23 = tid + 23*256; if (i23 < N_) cs[i23] = cSg[i23]; }
    __syncthreads();

    // ---- Phase A: nested-dominance DP (11 rounds) ----
    for (int s = tid; s < 512; s += 256)
        Ma[s] = (s < W_) ? (cs[rowstart_of(s)] & MAXK48) : MAXK48;
    __syncthreads();
    u64* Mcur = Ma; u64* Mnext = Mb;
    for (int l = 2; l <= 12; l++){
        #pragma unroll
        for (int q = 0; q < 2; q++){
            int s = tid + q*256;          // 0..511
            u64 key = MAXK48; int idx = -1;
            if (s + l <= W_){ idx = rowstart_of(s) + (l-1); key = cs[idx] & MAXK48; }
            u64 a = Mcur[s];
            u64 bb = (s + 1 < 512) ? Mcur[s+1] : MAXK48;
            u64 dom = a < bb ? a : bb;
            if (idx >= 0 && dom < key) cs[idx] = ~0ull;      // pruned
            Mnext[s] = dom < key ? dom : key;
        }
        __syncthreads();
        u64* t = Mcur; Mcur = Mnext; Mnext = t;
    }

    // ---- Phase B: in-place compaction (blocked, register-staged) ----
    {
        int base = tid*PT_;
        u64 vv[PT_];
        u32 flags = 0; int cnt = 0;
        #pragma unroll
        for (int k = 0; k < PT_; k++){
            int i = base + k;
            u64 v = (i < N_) ? cs[i] : ~0ull;
            vv[k] = v;
            if (v != ~0ull){ flags |= (1u << k); cnt++; }
        }
        u32 inc = (u32)cnt;
        for (int d = 1; d < 64; d <<= 1){ u32 o = (u32)__shfl_up((int)inc, d, 64); if (lane >= d) inc += o; }
        if (lane == 63) wtot[wave] = inc;
        __syncthreads();
        u32 woffs = 0;
        for (int w = 0; w < 4; w++) if (w < wave) woffs += wtot[w];
        u32 off = woffs + inc - (u32)cnt;
        if (tid == 255) nsh = (int)(woffs + inc);
        #pragma unroll
        for (int k = 0; k < PT_; k++){
            if (flags & (1u << k)) cs[off++] = vv[k];
        }
    }
    __syncthreads();
    int n = nsh;
    if (tid < 16) cs[n + tid] = ~0ull;     // pad for 16-wide batched reads
    __syncthreads();

    // ---- Phase C: rank-sort over low-48 keys ----
    if (n <= 1536){
        u64 v0=~0ull,v1=~0ull,v2=~0ull,v3=~0ull,v4=~0ull,v5=~0ull;
        u64 k0=0,k1=0,k2=0,k3=0,k4=0,k5=0;
        if (tid        < n){ v0 = cs[tid];        k0 = v0 & MAXK48; }
        if (tid +  256 < n){ v1 = cs[tid +  256]; k1 = v1 & MAXK48; }
        if (tid +  512 < n){ v2 = cs[tid +  512]; k2 = v2 & MAXK48; }
        if (tid +  768 < n){ v3 = cs[tid +  768]; k3 = v3 & MAXK48; }
        if (tid + 1024 < n){ v4 = cs[tid + 1024]; k4 = v4 & MAXK48; }
        if (tid + 1280 < n){ v5 = cs[tid + 1280]; k5 = v5 & MAXK48; }
        u32 r0=0,r1=0,r2=0,r3=0,r4=0,r5=0;
        for (int j = 0; j < n; j += 16){
            u64 c0 = cs[j+ 0]&MAXK48, c1 = cs[j+ 1]&MAXK48, c2 = cs[j+ 2]&MAXK48, c3 = cs[j+ 3]&MAXK48;
            u64 c4 = cs[j+ 4]&MAXK48, c5 = cs[j+ 5]&MAXK48, c6 = cs[j+ 6]&MAXK48, c7 = cs[j+ 7]&MAXK48;
            u64 c8 = cs[j+ 8]&MAXK48, c9 = cs[j+ 9]&MAXK48, cA = cs[j+10]&MAXK48, cB = cs[j+11]&MAXK48;
            u64 cC = cs[j+12]&MAXK48, cD = cs[j+13]&MAXK48, cE = cs[j+14]&MAXK48, cF = cs[j+15]&MAXK48;
            r0 += (u32)(c0<k0)+(u32)(c1<k0)+(u32)(c2<k0)+(u32)(c3<k0)+(u32)(c4<k0)+(u32)(c5<k0)+(u32)(c6<k0)+(u32)(c7<k0)
                + (u32)(c8<k0)+(u32)(c9<k0)+(u32)(cA<k0)+(u32)(cB<k0)+(u32)(cC<k0)+(u32)(cD<k0)+(u32)(cE<k0)+(u32)(cF<k0);
            r1 += (u32)(c0<k1)+(u32)(c1<k1)+(u32)(c2<k1)+(u32)(c3<k1)+(u32)(c4<k1)+(u32)(c5<k1)+(u32)(c6<k1)+(u32)(c7<k1)
                + (u32)(c8<k1)+(u32)(c9<k1)+(u32)(cA<k1)+(u32)(cB<k1)+(u32)(cC<k1)+(u32)(cD<k1)+(u32)(cE<k1)+(u32)(cF<k1);
            r2 += (u32)(c0<k2)+(u32)(c1<k2)+(u32)(c2<k2)+(u32)(c3<k2)+(u32)(c4<k2)+(u32)(c5<k2)+(u32)(c6<k2)+(u32)(c7<k2)
                + (u32)(c8<k2)+(u32)(c9<k2)+(u32)(cA<k2)+(u32)(cB<k2)+(u32)(cC<k2)+(u32)(cD<k2)+(u32)(cE<k2)+(u32)(cF<k2);
            r3 += (u32)(c0<k3)+(u32)(c1<k3)+(u32)(c2<k3)+(u32)(c3<k3)+(u32)(c4<k3)+(u32)(c5<k3)+(u32)(c6<k3)+(u32)(c7<k3)
                + (u32)(c8<k3)+(u32)(c9<k3)+(u32)(cA<k3)+(u32)(cB<k3)+(u32)(cC<k3)+(u32)(cD<k3)+(u32)(cE<k3)+(u32)(cF<k3);
            r4 += (u32)(c0<k4)+(u32)(c1<k4)+(u32)(c2<k4)+(u32)(c3<k4)+(u32)(c4<k4)+(u32)(c5<k4)+(u32)(c6<k4)+(u32)(c7<k4)
                + (u32)(c8<k4)+(u32)(c9<k4)+(u32)(cA<k4)+(u32)(cB<k4)+(u32)(cC<k4)+(u32)(cD<k4)+(u32)(cE<k4)+(u32)(cF<k4);
            r5 += (u32)(c0<k5)+(u32)(c1<k5)+(u32)(c2<k5)+(u32)(c3<k5)+(u32)(c4<k5)+(u32)(c5<k5)+(u32)(c6<k5)+(u32)(c7<k5)
                + (u32)(c8<k5)+(u32)(c9<k5)+(u32)(cA<k5)+(u32)(cB<k5)+(u32)(cC<k5)+(u32)(cD<k5)+(u32)(cE<k5)+(u32)(cF<k5);
        }
        __syncthreads();
        if (tid        < n) cs[r0] = v0;
        if (tid +  256 < n) cs[r1] = v1;
        if (tid +  512 < n) cs[r2] = v2;
        if (tid +  768 < n) cs[r3] = v3;
        if (tid + 1024 < n) cs[r4] = v4;
        if (tid + 1280 < n) cs[r5] = v5;
        __syncthreads();
    } else {
        // generic path (never expected; kept for correctness)
        u64 vv[PT_]; u32 rr[PT_];
        #pragma unroll
        for (int k = 0; k < PT_; k++){ vv[k] = ~0ull; rr[k] = 0; }
        #pragma unroll
        for (int k = 0; k < PT_; k++){
            int i = tid + (k << 8);
            if (i < n){
                u64 v = cs[i];
                vv[k] = v;
                u64 ki = v & MAXK48;
                u32 r = 0;
                for (int j = 0; j < n; j += 8){
                    u64 c0 = cs[j+0]&MAXK48, c1 = cs[j+1]&MAXK48;
                    u64 c2 = cs[j+2]&MAXK48, c3 = cs[j+3]&MAXK48;
                    u64 c4 = cs[j+4]&MAXK48, c5 = cs[j+5]&MAXK48;
                    u64 c6 = cs[j+6]&MAXK48, c7 = cs[j+7]&MAXK48;
                    r += (u32)(c0<ki) + (u32)(c1<ki) + (u32)(c2<ki) + (u32)(c3<ki)
                       + (u32)(c4<ki) + (u32)(c5<ki) + (u32)(c6<ki) + (u32)(c7<ki);
                }
                rr[k] = r;
            }
        }
        __syncthreads();
        #pragma unroll
        for (int k = 0; k < PT_; k++){
            int i = tid + (k << 8);
            if (i < n) cs[rr[k]] = vv[k];
        }
        __syncthreads();
    }

    // ---- write sorted stream + count to global ----
    for (int i = tid; i < n; i += 256) candO[(size_t)b*MAXC_ + i] = cs[i];
    if (tid == 0) cntp[b] = n;
}

// ---------------- tail B: decode only (1 wave/block; LDS-resident stream) --------------------
__global__ __launch_bounds__(64) void k_tailB(const u64* __restrict__ candO,
                                              const int* __restrict__ cntp,
                                              float* __restrict__ outSel){
    __shared__ u64 cs[MAXC_];
    int b = blockIdx.x; int lane = threadIdx.x;
    int n = cntp[b];
    const u64* src = candO + (size_t)b*MAXC_;
    for (int i = lane; i < n; i += 64) cs[i] = src[i];
    __syncthreads();
    decode_wave(cs, n, outSel, b);
}

extern "C" void kernel_launch(void* const* d_in, const int* in_sizes, int n_in,
                              void* d_out, int out_size, void* d_ws, size_t ws_size,
                              hipStream_t stream){
    const float* hs        = (const float*)d_in[0];
    const float* ent_w1    = (const float*)d_in[1];
    const float* ent_b1    = (const float*)d_in[2];
    const float* ent_w2    = (const float*)d_in[3];
    const float* ent_b2    = (const float*)d_in[4];
    const float* span_w1   = (const float*)d_in[5];
    const float* span_b1   = (const float*)d_in[6];
    const float* span_w2   = (const float*)d_in[7];
    const float* span_b2   = (const float*)d_in[8];
    const int*  text_mask  = (const int*)d_in[9];
    const int*  ent_mask   = (const int*)d_in[10];
    const int*  word_index = (const int*)d_in[11];
    float* out = (float*)d_out;

    // ---- workspace (~24.8 MB peak; candS/candO overlay dead wemb) ----
    char* wsbase = (char*)d_ws; size_t off = 0;
    auto alloc = [&](size_t bytes)->void*{ void* p = wsbase + off; off = (off + bytes + 255) & ~(size_t)255; return p; };
    char*  region1 = (char*)alloc((size_t)B_*W_*H_*4);    // 12,386,304 B
    float* wemb   = (float*)region1;                       // phase 1
    u64*   candS  = (u64*)region1;                         // phase 2: 382,848 B
    u64*   candO  = (u64*)(region1 + 393216);              // 393,216 B (sorted streams)
    int*   tok    = (int*)  alloc((size_t)B_*W_*4*4);
    int*   tokc   = (int*)  alloc((size_t)B_*W_*4);
    float* PQ     = (float*)alloc((size_t)4*W_*1024*4);    // 8,257,536 B (4 batches/pass)
    float* logits = (float*)alloc((size_t)BNE_*4);         // 3,062,784 B
    int*   entpos = (int*)  alloc((size_t)B_*E_*4);
    float* hidg   = (float*)alloc((size_t)B_*E_*DFF_*4);   // 262,144 B
    float* entvec = (float*)alloc((size_t)B_*E_*H_*4);
    float* Mmat   = (float*)alloc((size_t)B_*DFF_*E_*4);
    float* cvec   = (float*)alloc((size_t)B_*E_*4);
    int*   starts = (int*)  alloc((size_t)N_*4);
    int*   ends   = (int*)  alloc((size_t)N_*4);
    int*   cntp   = (int*)  alloc((size_t)B_*4);

    k_prolog<<<9,256,0,stream>>>(ent_mask, entpos, starts, ends, tokc);
    k_toklist<<<(B_*L_+255)/256,256,0,stream>>>(text_mask, word_index, tok, tokc);
    k_poolsort<<<B_*W_,256,0,stream>>>(hs, tok, tokc, wemb);
    k_ent1<<<B_*E_*2,256,0,stream>>>(hs, entpos, ent_w1, ent_b1, hidg);
    k_ent2<<<B_*E_*3,256,0,stream>>>(hidg, ent_w2, ent_b2, entvec);
    k_Mc<<<257,256,0,stream>>>(span_w2, span_b2, entvec, Mmat, cvec);
    for (int b0 = 0; b0 < B_; b0 += 4){
        k_pq<<<512,256,0,stream>>>(wemb, span_w1, PQ, b0);
        k_logits<<<4*W_,256,0,stream>>>(PQ, Mmat, cvec, span_b1, logits, out, b0);
    }
    // wemb dead from here; region1 hosts candS/candO
    k_spanbest<<<(B_*N_+255)/256,256,0,stream>>>(logits, starts, ends, candS, out);
    k_tailA<<<B_,256,0,stream>>>(candS, candO, cntp);
    k_tailB<<<B_,64,0,stream>>>(candO, cntp, out);
}

// Round 10
// 429.151 us; speedup vs baseline: 1.0329x; 1.0329x over previous
//
#include <hip/hip_runtime.h>
#include <hip/hip_bf16.h>
#include <stdint.h>

#define B_ 8
#define L_ 1024
#define H_ 768
#define E_ 16
#define W_ 504
#define DFF_ 512
#define N_ 5982
#define NE_ (N_*E_)    // 95712 candidates per batch
#define BNE_ (B_*NE_)  // 765696
#define MAXC_ 6144
#define MAXK48 0x0000FFFFFFFFFFFFull
#define PT_ 24         // per-thread elements in k_tailA (24*256 = 6144 >= N_)

typedef unsigned long long u64;
typedef unsigned int u32;

__device__ __forceinline__ int rowstart_of(int s){
    int s0 = W_ - 11; // 493
    if (s <= s0) return 12*s;
    int t = s - s0;
    return 12*s0 + t*11 - (t*(t-1))/2;
}

__device__ __forceinline__ u64 shflup_u64(u64 x, int d){
    u32 lo = (u32)__shfl_up((int)(u32)x, d, 64);
    u32 hi = (u32)__shfl_up((int)(u32)(x >> 32), d, 64);
    return ((u64)hi << 32) | (u64)lo;
}
__device__ __forceinline__ u64 shflxor_u64(u64 x, int m){
    u32 lo = (u32)__shfl_xor((int)(u32)x, m, 64);
    u32 hi = (u32)__shfl_xor((int)(u32)(x >> 32), m, 64);
    return ((u64)hi << 32) | (u64)lo;
}

// ---------------- prolog: span tables + tokc zero (block 8), parallel entpos (blocks 0..7) ----
__global__ void k_prolog(const int* __restrict__ ent_mask, int* __restrict__ ent_pos,
                         int* __restrict__ starts, int* __restrict__ ends,
                         int* __restrict__ tokc){
    int blk = blockIdx.x; int tid = threadIdx.x;
    if (blk == 8){
        for (int s = tid; s < W_; s += 256){
            int rs = rowstart_of(s);
            int cnt = min(12, W_ - s);
            for (int i = 0; i < cnt; i++){ starts[rs+i] = s; ends[rs+i] = s+i; }
        }
        for (int i = tid; i < B_*W_; i += 256) tokc[i] = 0;
        return;
    }
    __shared__ u32 wt[4]; __shared__ u32 cbase;
    int b = blk;
    int lane = tid & 63, wave = tid >> 6;
    if (tid == 0) cbase = 0;
    __syncthreads();
    for (int base = 0; base < L_; base += 256){
        int l = base + tid;
        bool f = (ent_mask[b*L_ + l] == 1);
        u64 bal = __ballot(f);
        if (lane == 0) wt[wave] = (u32)__popcll(bal);
        __syncthreads();
        u32 pre = cbase;
        for (int w = 0; w < 4; w++) if (w < wave) pre += wt[w];
        if (f){
            u32 rank = pre + (u32)__popcll(bal & ((1ull<<lane)-1ull));
            if (rank < E_) ent_pos[b*E_ + rank] = l;
        }
        __syncthreads();
        if (tid == 0){ u32 r = cbase; for (int w = 0; w < 4; w++) r += wt[w]; cbase = r; }
        __syncthreads();
    }
    u32 totEnt = cbase;
    if (totEnt >= E_) return;                 // block-uniform
    for (int base = 0; base < L_; base += 256){
        int l = base + tid;
        bool f = (ent_mask[b*L_ + l] != 1);
        u64 bal = __ballot(f);
        if (lane == 0) wt[wave] = (u32)__popcll(bal);
        __syncthreads();
        u32 pre = cbase;
        for (int w = 0; w < 4; w++) if (w < wave) pre += wt[w];
        if (f){
            u32 rank = pre + (u32)__popcll(bal & ((1ull<<lane)-1ull));
            if (rank < E_) ent_pos[b*E_ + rank] = l;
        }
        __syncthreads();
        if (tid == 0){ u32 r = cbase; for (int w = 0; w < 4; w++) r += wt[w]; cbase = r; }
        __syncthreads();
    }
}

// ---------------- token lists: parallel build ----------------
__global__ void k_toklist(const int* __restrict__ tm, const int* __restrict__ wi,
                          int* __restrict__ tok, int* __restrict__ tokc){
    int i = blockIdx.x*256 + threadIdx.x;
    if (i >= B_*L_) return;
    int w = wi[i];
    if (tm[i] == 1 && w >= 0 && w < W_){
        int b = i / L_;
        int bw = b*W_ + w;
        int pos = atomicAdd(&tokc[bw], 1);
        if (pos < 4) tok[bw*4 + pos] = i - b*L_;
    }
}

// ---------------- fused per-word sort + mean pooling (one block per (b,w)) ----------------
__global__ void k_poolsort(const float* __restrict__ hs, const int* __restrict__ tok,
                           const int* __restrict__ tokc, float* __restrict__ wemb){
    __shared__ int stok[4]; __shared__ int scnt;
    int bw = blockIdx.x;                       // B_*W_
    int b = bw / W_;
    int tid = threadIdx.x;
    if (tid == 0){
        int c = tokc[bw]; int cc = min(c, 4);
        int v[4];
        for (int k = 0; k < cc; k++) v[k] = tok[bw*4 + k];
        for (int a = 1; a < cc; a++){ int x = v[a]; int j = a-1; while (j >= 0 && v[j] > x){ v[j+1] = v[j]; j--; } v[j+1] = x; }
        for (int k = 0; k < cc; k++) stok[k] = v[k];
        scnt = c;
    }
    __syncthreads();
    int c = scnt; int cc = min(c, 4);
    float denom = (float)max(c, 1);
    for (int h = tid; h < H_; h += 256){
        double s = 0.0;
        for (int k = 0; k < cc; k++)
            s += (double)hs[((size_t)(b*L_ + stok[k]))*H_ + h];
        wemb[(size_t)bw*H_ + h] = (float)(s / (double)denom);
    }
}

// ---------------- entity MLP layer 1 (one output/thread; deep load pipeline) ----------------
__global__ void k_ent1(const float* __restrict__ hs, const int* __restrict__ ent_pos,
                       const float* __restrict__ w1, const float* __restrict__ b1,
                       float* __restrict__ hidg){
    __shared__ float x[H_];
    int blk = blockIdx.x;            // 256 blocks: be*2 + half
    int be = blk >> 1; int half = blk & 1;
    int b = be >> 4;
    int tid = threadIdx.x;
    int pos = ent_pos[be];
    const float* xp = hs + ((size_t)b*L_ + pos)*H_;
    for (int j = tid; j < H_; j += 256) x[j] = xp[j];
    __syncthreads();
    int d = half*256 + tid;
    float a0=0.f,a1=0.f,a2=0.f,a3=0.f;
    const float* wp = w1 + d;
    #pragma unroll 8
    for (int h = 0; h < H_; h += 4){
        a0 += x[h+0]*wp[(size_t)(h+0)*DFF_];
        a1 += x[h+1]*wp[(size_t)(h+1)*DFF_];
        a2 += x[h+2]*wp[(size_t)(h+2)*DFF_];
        a3 += x[h+3]*wp[(size_t)(h+3)*DFF_];
    }
    float acc = ((a0+a1)+(a2+a3)) + b1[d];
    hidg[(size_t)be*DFF_ + d] = acc > 0.f ? acc : 0.01f*acc;
}

// ---------------- entity MLP layer 2 (one output/thread; deep load pipeline) ----------------
__global__ void k_ent2(const float* __restrict__ hidg,
                       const float* __restrict__ w2, const float* __restrict__ b2,
                       float* __restrict__ ent_vec){
    __shared__ float hsd[DFF_];
    int blk = blockIdx.x;            // 384 blocks: be*3 + third
    int be = blk / 3; int third = blk % 3;
    int tid = threadIdx.x;
    const float* hp = hidg + (size_t)be*DFF_;
    for (int j = tid; j < DFF_; j += 256) hsd[j] = hp[j];
    __syncthreads();
    int j = third*256 + tid;
    float a0=0.f,a1=0.f,a2=0.f,a3=0.f;
    const float* wp = w2 + j;
    #pragma unroll 8
    for (int d = 0; d < DFF_; d += 4){
        a0 += hsd[d+0]*wp[(size_t)(d+0)*H_];
        a1 += hsd[d+1]*wp[(size_t)(d+1)*H_];
        a2 += hsd[d+2]*wp[(size_t)(d+2)*H_];
        a3 += hsd[d+3]*wp[(size_t)(d+3)*H_];
    }
    ent_vec[(size_t)be*H_ + j] = ((a0+a1)+(a2+a3)) + b2[j];
}

// ---------------- fused M + c: blocks 0..255 = M, block 256 = c (fp64, decode-critical) ------
__global__ void k_Mc(const float* __restrict__ span_w2, const float* __restrict__ span_b2,
                     const float* __restrict__ ent_vec, float* __restrict__ M,
                     float* __restrict__ cvec){
    int blk = blockIdx.x;
    if (blk == 256){
        int i = threadIdx.x;
        if (i < B_*E_){
            const float* ev = ent_vec + (size_t)i*H_;
            double acc = 0.0;
            for (int h = 0; h < H_; h++) acc += (double)span_b2[h]*(double)ev[h];
            cvec[i] = (float)acc;
        }
        return;
    }
    int b = blk/32; int dbase = (blk%32)*16;
    int tid = threadIdx.x; int d = dbase + (tid>>4); int e = tid&15;
    const float* ev = ent_vec + ((size_t)b*E_ + e)*H_;
    const float* wr = span_w2 + (size_t)d*H_;
    double p0=0.0, p1=0.0;
    for (int h = 0; h < H_; h += 2){
        p0 += (double)wr[h]*(double)ev[h];
        p1 += (double)wr[h+1]*(double)ev[h+1];
    }
    M[((size_t)b*DFF_ + d)*E_ + e] = (float)(p0+p1);
}

// ---------------- P/Q projection: BK=32 + register-prefetch double buffering ----------------
// Per-output K-accumulation order identical to the BK=16 version (k ascending, same FMA
// sequence) -> bit-identical PQ. Loads for chunk k+1 issue before chunk k's compute.
__global__ void k_pq(const float* __restrict__ wemb, const float* __restrict__ w1,
                     float* __restrict__ PQ, int b0){
    __shared__ float As[32][68];
    __shared__ float Bs[32][68];
    int bx = blockIdx.x & 15;      // col tile
    int by = blockIdx.x >> 4;      // row tile (0..31)
    int tid = threadIdx.x;
    int tm = tid >> 4, tn = tid & 15;
    const float* A0 = wemb + (size_t)b0*W_*H_;
    int colbase = bx*64;
    const float* Bbase = (colbase < DFF_) ? w1 : (w1 + (size_t)H_*DFF_);
    int bcol0 = (colbase < DFF_) ? colbase : (colbase - DFF_);
    float acc[4][4] = {{0.f}};
    int ar = tid >> 2, akq = tid & 3;
    int bkk = tid >> 4, bcq = tid & 15;
    const int ROWS = 4*W_;         // 2016
    int gr = by*64 + ar;
    bool aok = (gr < ROWS);
    const float* Ap = A0 + (size_t)gr*H_ + akq*4;
    const float* Bp = Bbase + (size_t)bkk*DFF_ + bcol0 + bcq*4;
    float4 av0, av1, bv0, bv1;
    // prologue: chunk 0
    av0 = aok ? *(const float4*)(Ap + 0)  : make_float4(0.f,0.f,0.f,0.f);
    av1 = aok ? *(const float4*)(Ap + 16) : make_float4(0.f,0.f,0.f,0.f);
    bv0 = *(const float4*)(Bp + 0);
    bv1 = *(const float4*)(Bp + (size_t)16*DFF_);
    for (int k0 = 0; k0 < H_; k0 += 32){
        As[akq*4+0][ar] = av0.x; As[akq*4+1][ar] = av0.y;
        As[akq*4+2][ar] = av0.z; As[akq*4+3][ar] = av0.w;
        As[16+akq*4+0][ar] = av1.x; As[16+akq*4+1][ar] = av1.y;
        As[16+akq*4+2][ar] = av1.z; As[16+akq*4+3][ar] = av1.w;
        Bs[bkk][bcq*4+0] = bv0.x; Bs[bkk][bcq*4+1] = bv0.y;
        Bs[bkk][bcq*4+2] = bv0.z; Bs[bkk][bcq*4+3] = bv0.w;
        Bs[16+bkk][bcq*4+0] = bv1.x; Bs[16+bkk][bcq*4+1] = bv1.y;
        Bs[16+bkk][bcq*4+2] = bv1.z; Bs[16+bkk][bcq*4+3] = bv1.w;
        __syncthreads();
        if (k0 + 32 < H_){        // prefetch next chunk; latency hides under compute
            int kn = k0 + 32;
            av0 = aok ? *(const float4*)(Ap + kn)      : make_float4(0.f,0.f,0.f,0.f);
            av1 = aok ? *(const float4*)(Ap + kn + 16) : make_float4(0.f,0.f,0.f,0.f);
            bv0 = *(const float4*)(Bp + (size_t)kn*DFF_);
            bv1 = *(const float4*)(Bp + (size_t)(kn+16)*DFF_);
        }
        #pragma unroll
        for (int kk = 0; kk < 32; kk++){
            float4 a = *(const float4*)&As[kk][tm*4];
            float4 bv = *(const float4*)&Bs[kk][tn*4];
            acc[0][0] += a.x*bv.x; acc[0][1] += a.x*bv.y; acc[0][2] += a.x*bv.z; acc[0][3] += a.x*bv.w;
            acc[1][0] += a.y*bv.x; acc[1][1] += a.y*bv.y; acc[1][2] += a.y*bv.z; acc[1][3] += a.y*bv.w;
            acc[2][0] += a.z*bv.x; acc[2][1] += a.z*bv.y; acc[2][2] += a.z*bv.z; acc[2][3] += a.z*bv.w;
            acc[3][0] += a.w*bv.x; acc[3][1] += a.w*bv.y; acc[3][2] += a.w*bv.z; acc[3][3] += a.w*bv.w;
        }
        __syncthreads();
    }
    #pragma unroll
    for (int r = 0; r < 4; r++){
        int grr = by*64 + tm*4 + r;
        if (grr < ROWS){
            float4 ov = make_float4(acc[r][0], acc[r][1], acc[r][2], acc[r][3]);
            *(float4*)(PQ + (size_t)grr*1024 + colbase + tn*4) = ov;
        }
    }
}

// ---------------- logits: one block per (bl, s); 4-way fp64 accum + wave-shuffle reduce ------
__global__ void k_logits(const float* __restrict__ PQ, const float* __restrict__ Mmat,
                         const float* __restrict__ cvec, const float* __restrict__ span_b1,
                         float* __restrict__ logits, float* __restrict__ outL, int b0){
    __shared__ float Ps[DFF_];
    __shared__ float hid[DFF_];
    __shared__ double redw[64];
    __shared__ float csh[E_];
    int blk = blockIdx.x;            // 4*W_ blocks
    int bl = blk / W_; int s = blk - bl*W_;
    int b = b0 + bl;
    int tid = threadIdx.x;
    int lane = tid & 63, wave = tid >> 6;
    int ee = tid & 15; int g = tid >> 4;   // 16 groups x 32 d
    float Mreg[32];
    {
        const float* Mp = Mmat + (size_t)b*DFF_*E_ + (size_t)(g*32)*E_ + ee;
        #pragma unroll
        for (int i = 0; i < 32; i++) Mreg[i] = Mp[(size_t)i*E_];
    }
    const float* P = PQ + ((size_t)(bl*W_ + s))*1024;
    for (int d = tid; d < DFF_; d += 256) Ps[d] = P[d] + span_b1[d];
    if (tid < E_) csh[tid] = cvec[b*E_ + tid];
    __syncthreads();
    int nsp = min(12, W_ - s);
    int nbase = rowstart_of(s);
    for (int i = 0; i < nsp; i++){
        int e = s + i;
        const float* Q = PQ + ((size_t)(bl*W_ + e))*1024 + DFF_;
        for (int d = tid; d < DFF_; d += 256){
            float h = Ps[d] + Q[d];
            hid[d] = h > 0.f ? h : 0.01f*h;
        }
        __syncthreads();
        {
            int d0 = g*32;
            double a0=0.0, a1=0.0, a2=0.0, a3=0.0;   // 4 chains break the serial FMA dep
            #pragma unroll
            for (int k = 0; k < 32; k += 4){
                a0 += (double)hid[d0+k+0]*(double)Mreg[k+0];
                a1 += (double)hid[d0+k+1]*(double)Mreg[k+1];
                a2 += (double)hid[d0+k+2]*(double)Mreg[k+2];
                a3 += (double)hid[d0+k+3]*(double)Mreg[k+3];
            }
            double acc = (a0+a1)+(a2+a3);
            double t = acc + __shfl_down(acc, 32, 64);
            t = t + __shfl_down(t, 16, 64);
            if (lane < 16) redw[wave*16 + lane] = t;
        }
        __syncthreads();
        if (tid < E_){
            double t = ((redw[tid] + redw[16+tid]) + (redw[32+tid] + redw[48+tid]))
                     + (double)csh[tid];
            float lg = (float)t;
            size_t oi = ((size_t)b*N_ + nbase + i)*E_ + tid;
            logits[oi] = lg;
            outL[oi] = lg;
        }
        __syncthreads();
    }
}

// ---------------- per-span best candidate + selected-region zeroing ----------------
__global__ void k_spanbest(const float* __restrict__ logits,
                           const int* __restrict__ starts, const int* __restrict__ ends,
                           u64* __restrict__ candS, float* __restrict__ outSel){
    int idx = blockIdx.x*256 + threadIdx.x;      // over B_*N_
    if (idx >= B_*N_) return;
    int b = idx / N_; int n = idx - b*N_;
    const float* lg = logits + (size_t)b*NE_ + (size_t)n*16;
    u64 best = ~0ull;
    for (int e = 0; e < 16; e++){
        float prob = 1.0f/(1.0f + expf(-lg[e]));
        if (prob > 0.5f){
            u32 key24 = (~__float_as_uint(prob)) & 0xFFFFFFu;
            u64 pk = ((u64)key24 << 24) | (u64)(u32)(n*16 + e);
            best = best < pk ? best : pk;
        }
    }
    int s = starts[n], e2 = ends[n];
    int len = e2 - s + 1;
    u64 packed = best;
    if (best != ~0ull)
        packed = best | ((u64)(u32)s << 48) | ((u64)(u32)(len-1) << 57);
    candS[idx] = packed;
    float* selp = outSel + (size_t)BNE_ + (size_t)b*NE_ + (size_t)n*16;
    float4 z = make_float4(0.f,0.f,0.f,0.f);
    *(float4*)(selp+0)  = z; *(float4*)(selp+4)  = z;
    *(float4*)(selp+8)  = z; *(float4*)(selp+12) = z;
}

// ---------------- greedy decode: wave-parallel prefix-OR rounds + serial pending -------------
__device__ __forceinline__ void decode_wave(const u64* sp, int n,
                                            float* __restrict__ outSel, int b){
    int lane = threadIdx.x & 63;
    u64 scov[8];
    #pragma unroll
    for (int k = 0; k < 8; k++) scov[k] = 0ull;
    int covcnt = 0;
    for (int base = 0; base < n; base += 64){
        int i = base + lane;
        bool has = i < n;
        u64 v = has ? sp[i] : ~0ull;
        int s   = (int)((v >> 48) & 0x1FFull);
        int len = (int)((v >> 57) & 0xFull) + 1;
        u32 c   = (u32)(v & 0xFFFFFFull);
        int w0 = s >> 6, sh0 = s & 63;
        int w1i = (w0 < 7) ? w0 + 1 : 7;
        u64 full = (1ull << len) - 1ull;
        u64 m0 = has ? (full << sh0) : 0ull;
        u64 m1 = (has && sh0 + len > 64) ? (full >> (64 - sh0)) : 0ull;
        u64 myc0 = 0ull, myc1 = 0ull;
        #pragma unroll
        for (int k = 0; k < 8; k++){
            if (w0  == k) myc0 = scov[k];
            if (w1i == k) myc1 = scov[k];
        }
        bool alive = has && (((myc0 & m0) | (myc1 & m1)) == 0ull);
        bool accept = false;
        u64 balv = __ballot(alive);
        if (balv){
            u64 pm[8];
            #pragma unroll
            for (int k = 0; k < 8; k++){
                u64 t = 0ull;
                if (alive){
                    if (w0  == k) t |= m0;
                    if (w1i == k) t |= m1;
                }
                pm[k] = t;
            }
            #pragma unroll
            for (int st = 1; st < 64; st <<= 1){
                #pragma unroll
                for (int k = 0; k < 8; k++) pm[k] |= shflup_u64(pm[k], st);
            }
            u64 ex0 = 0ull, ex1 = 0ull;
            #pragma unroll
            for (int k = 0; k < 8; k++){
                u64 e = shflup_u64(pm[k], 1);
                e = (lane == 0) ? 0ull : e;
                if (w0  == k) ex0 = e;
                if (w1i == k) ex1 = e;
            }
            bool blocked = (((ex0 & m0) | (ex1 & m1)) != 0ull);
            bool newacc = alive && !blocked;
            accept = newacc;
            u64 am[8];
            #pragma unroll
            for (int k = 0; k < 8; k++){
                u64 t = 0ull;
                if (newacc){
                    if (w0  == k) t |= m0;
                    if (w1i == k) t |= m1;
                }
                am[k] = t;
            }
            #pragma unroll
            for (int st = 1; st < 64; st <<= 1){
                #pragma unroll
                for (int k = 0; k < 8; k++) am[k] |= shflxor_u64(am[k], st);
            }
            #pragma unroll
            for (int k = 0; k < 8; k++){
                covcnt += (int)__popcll(am[k]);
                scov[k] |= am[k];
            }
            u64 pend = __ballot(alive && blocked);
            u32 vlo = (u32)v, vhi = (u32)(v >> 32);
            u64 accm = 0ull;
            while (pend){
                int j = (int)__builtin_ctzll(pend);
                pend &= pend - 1ull;
#if __has_builtin(__builtin_amdgcn_readlane)
                u32 jlo = (u32)__builtin_amdgcn_readlane((int)vlo, j);
                u32 jhi = (u32)__builtin_amdgcn_readlane((int)vhi, j);
#else
                u32 jlo = (u32)__shfl((int)vlo, j, 64);
                u32 jhi = (u32)__shfl((int)vhi, j, 64);
#endif
                u64 jv = ((u64)jhi << 32) | (u64)jlo;
                int js   = (int)((jv >> 48) & 0x1FFull);
                int jlen = (int)((jv >> 57) & 0xFull) + 1;
                int jw0 = js >> 6, jsh = js & 63;
                int jw1 = (jw0 < 7) ? jw0 + 1 : 7;
                u64 jfull = (1ull << jlen) - 1ull;
                u64 jm0 = jfull << jsh;
                u64 jm1 = (jsh + jlen > 64) ? (jfull >> (64 - jsh)) : 0ull;
                u64 c0 = 0ull, c1 = 0ull;
                #pragma unroll
                for (int k = 0; k < 8; k++){
                    if (jw0 == k) c0 = scov[k];
                    if (jw1 == k) c1 = scov[k];
                }
                bool ok = (((c0 & jm0) | (c1 & jm1)) == 0ull);
                u64 okm = ok ? ~0ull : 0ull;
                #pragma unroll
                for (int k = 0; k < 8; k++){
                    u64 add = 0ull;
                    if (jw0 == k) add |= jm0;
                    if (jw1 == k) add |= jm1;
                    scov[k] |= (add & okm);
                }
                covcnt += ok ? jlen : 0;
                accm |= (okm & (1ull << j));
            }
            if (((accm >> lane) & 1ull) != 0ull) accept = true;
        }
        if (accept)
            outSel[(size_t)BNE_ + (size_t)b*NE_ + (size_t)c] = 1.0f;
        if (covcnt >= W_) break;
    }
}

// ---------------- tail A: load -> DP -> clean-prune -> compact -> rank-sort -> write ---------
__global__ __launch_bounds__(256) void k_tailA(const u64* __restrict__ candS,
                                               u64* __restrict__ candO, int* __restrict__ cntp){
    __shared__ u64 cs[6032];          // candidate table, then compacted+sorted (+pad 16)
    __shared__ u64 Ma[512], Mb[512];  // DP ping-pong; later mcov / ckey
    __shared__ u32 wtot[4];
    __shared__ int nsh;
    int b = blockIdx.x; int tid = threadIdx.x;
    int lane = tid & 63, wave = tid >> 6;
    const u64* cSg = candS + (size_t)b*N_;

    // ---- load table -> LDS (fully unrolled: 24 independent loads in flight) ----
    #pragma unroll
    for (int k = 0; k < 23; k++) cs[tid + k*256] = cSg[tid + k*256];
    { int i23 = tid + 23*256; if (i23 < N_) cs[i23] = cSg[i23]; }
    __syncthreads();

    // ---- Phase A: nested-dominance DP (11 rounds) ----
    for (int s = tid; s < 512; s += 256)
        Ma[s] = (s < W_) ? (cs[rowstart_of(s)] & MAXK48) : MAXK48;
    __syncthreads();
    u64* Mcur = Ma; u64* Mnext = Mb;
    for (int l = 2; l <= 12; l++){
        #pragma unroll
        for (int q = 0; q < 2; q++){
            int s = tid + q*256;          // 0..511
            u64 key = MAXK48; int idx = -1;
            if (s + l <= W_){ idx = rowstart_of(s) + (l-1); key = cs[idx] & MAXK48; }
            u64 a = Mcur[s];
            u64 bb = (s + 1 < 512) ? Mcur[s+1] : MAXK48;
            u64 dom = a < bb ? a : bb;
            if (idx >= 0 && dom < key) cs[idx] = ~0ull;      // pruned
            Mnext[s] = dom < key ? dom : key;
        }
        __syncthreads();
        u64* t = Mcur; Mcur = Mnext; Mnext = t;
    }
    __syncthreads();

    // ---- Phase A2: clean-candidate pruning (exact) ----
    // A candidate j with no earlier-ranked overlapping candidate ("clean") is guaranteed
    // ACCEPTED by the greedy; every later-ranked candidate overlapping span(j) is then
    // guaranteed REJECTED -> delete. Clean candidates covering a word are unique (two would
    // overlap each other -> the later one isn't clean). Excluding already-killed candidates
    // from mcov is valid: they are guaranteed-rejected and cannot block anything.
    {
        // mcov(w) = min key over surviving candidates covering w   -> Ma
        for (int w = tid; w < 512; w += 256){
            u64 m = ~0ull;
            if (w < W_){
                int slo = (w > 11) ? (w - 11) : 0;
                for (int s = slo; s <= w; s++){
                    int rs = rowstart_of(s);
                    int lmax = min(12, W_ - s);
                    for (int l = w - s + 1; l <= lmax; l++){
                        u64 kk2 = cs[rs + l - 1] & MAXK48;   // killed -> MAXK48 (infinity)
                        if (kk2 < m) m = kk2;
                    }
                }
            }
            Ma[w] = m;
        }
        for (int w = tid; w < 512; w += 256) Mb[w] = ~0ull;  // ckey init
        __syncthreads();
        // mark clean candidates; scatter their keys (unique writer per word)
        for (int k = 0; k < PT_; k++){
            int i = tid + (k << 8);
            if (i < N_){
                u64 v = cs[i];
                if (v != ~0ull){
                    int s = (int)((v >> 48) & 0x1FFull);
                    int len = (int)((v >> 57) & 0xFull) + 1;
                    u64 key = v & MAXK48;
                    u64 rmin = ~0ull;
                    for (int w = s; w < s + len; w++){ u64 t = Ma[w]; if (t < rmin) rmin = t; }
                    if (rmin == key){
                        for (int w = s; w < s + len; w++) Mb[w] = key;
                    }
                }
            }
        }
        __syncthreads();
        // kill candidates overlapping an earlier-ranked clean candidate
        for (int k = 0; k < PT_; k++){
            int i = tid + (k << 8);
            if (i < N_){
                u64 v = cs[i];
                if (v != ~0ull){
                    int s = (int)((v >> 48) & 0x1FFull);
                    int len = (int)((v >> 57) & 0xFull) + 1;
                    u64 key = v & MAXK48;
                    bool kill = false;
                    for (int w = s; w < s + len; w++) kill = kill || (Mb[w] < key);
                    if (kill) cs[i] = ~0ull;
                }
            }
        }
        __syncthreads();
    }

    // ---- Phase B: in-place compaction (blocked, register-staged) ----
    {
        int base = tid*PT_;
        u64 vv[PT_];
        u32 flags = 0; int cnt = 0;
        #pragma unroll
        for (int k = 0; k < PT_; k++){
            int i = base + k;
            u64 v = (i < N_) ? cs[i] : ~0ull;
            vv[k] = v;
            if (v != ~0ull){ flags |= (1u << k); cnt++; }
        }
        u32 inc = (u32)cnt;
        for (int d = 1; d < 64; d <<= 1){ u32 o = (u32)__shfl_up((int)inc, d, 64); if (lane >= d) inc += o; }
        if (lane == 63) wtot[wave] = inc;
        __syncthreads();
        u32 woffs = 0;
        for (int w = 0; w < 4; w++) if (w < wave) woffs += wtot[w];
        u32 off = woffs + inc - (u32)cnt;
        if (tid == 255) nsh = (int)(woffs + inc);
        #pragma unroll
        for (int k = 0; k < PT_; k++){
            if (flags & (1u << k)) cs[off++] = vv[k];
        }
    }
    __syncthreads();
    int n = nsh;
    if (tid < 16) cs[n + tid] = ~0ull;     // pad for 16-wide batched reads
    __syncthreads();

    // ---- Phase C: rank-sort over low-48 keys ----
    if (n <= 1536){
        u64 v0=~0ull,v1=~0ull,v2=~0ull,v3=~0ull,v4=~0ull,v5=~0ull;
        u64 k0=0,k1=0,k2=0,k3=0,k4=0,k5=0;
        if (tid        < n){ v0 = cs[tid];        k0 = v0 & MAXK48; }
        if (tid +  256 < n){ v1 = cs[tid +  256]; k1 = v1 & MAXK48; }
        if (tid +  512 < n){ v2 = cs[tid +  512]; k2 = v2 & MAXK48; }
        if (tid +  768 < n){ v3 = cs[tid +  768]; k3 = v3 & MAXK48; }
        if (tid + 1024 < n){ v4 = cs[tid + 1024]; k4 = v4 & MAXK48; }
        if (tid + 1280 < n){ v5 = cs[tid + 1280]; k5 = v5 & MAXK48; }
        u32 r0=0,r1=0,r2=0,r3=0,r4=0,r5=0;
        for (int j = 0; j < n; j += 16){
            u64 c0 = cs[j+ 0]&MAXK48, c1 = cs[j+ 1]&MAXK48, c2 = cs[j+ 2]&MAXK48, c3 = cs[j+ 3]&MAXK48;
            u64 c4 = cs[j+ 4]&MAXK48, c5 = cs[j+ 5]&MAXK48, c6 = cs[j+ 6]&MAXK48, c7 = cs[j+ 7]&MAXK48;
            u64 c8 = cs[j+ 8]&MAXK48, c9 = cs[j+ 9]&MAXK48, cA = cs[j+10]&MAXK48, cB = cs[j+11]&MAXK48;
            u64 cC = cs[j+12]&MAXK48, cD = cs[j+13]&MAXK48, cE = cs[j+14]&MAXK48, cF = cs[j+15]&MAXK48;
            r0 += (u32)(c0<k0)+(u32)(c1<k0)+(u32)(c2<k0)+(u32)(c3<k0)+(u32)(c4<k0)+(u32)(c5<k0)+(u32)(c6<k0)+(u32)(c7<k0)
                + (u32)(c8<k0)+(u32)(c9<k0)+(u32)(cA<k0)+(u32)(cB<k0)+(u32)(cC<k0)+(u32)(cD<k0)+(u32)(cE<k0)+(u32)(cF<k0);
            r1 += (u32)(c0<k1)+(u32)(c1<k1)+(u32)(c2<k1)+(u32)(c3<k1)+(u32)(c4<k1)+(u32)(c5<k1)+(u32)(c6<k1)+(u32)(c7<k1)
                + (u32)(c8<k1)+(u32)(c9<k1)+(u32)(cA<k1)+(u32)(cB<k1)+(u32)(cC<k1)+(u32)(cD<k1)+(u32)(cE<k1)+(u32)(cF<k1);
            r2 += (u32)(c0<k2)+(u32)(c1<k2)+(u32)(c2<k2)+(u32)(c3<k2)+(u32)(c4<k2)+(u32)(c5<k2)+(u32)(c6<k2)+(u32)(c7<k2)
                + (u32)(c8<k2)+(u32)(c9<k2)+(u32)(cA<k2)+(u32)(cB<k2)+(u32)(cC<k2)+(u32)(cD<k2)+(u32)(cE<k2)+(u32)(cF<k2);
            r3 += (u32)(c0<k3)+(u32)(c1<k3)+(u32)(c2<k3)+(u32)(c3<k3)+(u32)(c4<k3)+(u32)(c5<k3)+(u32)(c6<k3)+(u32)(c7<k3)
                + (u32)(c8<k3)+(u32)(c9<k3)+(u32)(cA<k3)+(u32)(cB<k3)+(u32)(cC<k3)+(u32)(cD<k3)+(u32)(cE<k3)+(u32)(cF<k3);
            r4 += (u32)(c0<k4)+(u32)(c1<k4)+(u32)(c2<k4)+(u32)(c3<k4)+(u32)(c4<k4)+(u32)(c5<k4)+(u32)(c6<k4)+(u32)(c7<k4)
                + (u32)(c8<k4)+(u32)(c9<k4)+(u32)(cA<k4)+(u32)(cB<k4)+(u32)(cC<k4)+(u32)(cD<k4)+(u32)(cE<k4)+(u32)(cF<k4);
            r5 += (u32)(c0<k5)+(u32)(c1<k5)+(u32)(c2<k5)+(u32)(c3<k5)+(u32)(c4<k5)+(u32)(c5<k5)+(u32)(c6<k5)+(u32)(c7<k5)
                + (u32)(c8<k5)+(u32)(c9<k5)+(u32)(cA<k5)+(u32)(cB<k5)+(u32)(cC<k5)+(u32)(cD<k5)+(u32)(cE<k5)+(u32)(cF<k5);
        }
        __syncthreads();
        if (tid        < n) cs[r0] = v0;
        if (tid +  256 < n) cs[r1] = v1;
        if (tid +  512 < n) cs[r2] = v2;
        if (tid +  768 < n) cs[r3] = v3;
        if (tid + 1024 < n) cs[r4] = v4;
        if (tid + 1280 < n) cs[r5] = v5;
        __syncthreads();
    } else {
        // generic path (never expected; kept for correctness)
        u64 vv[PT_]; u32 rr[PT_];
        #pragma unroll
        for (int k = 0; k < PT_; k++){ vv[k] = ~0ull; rr[k] = 0; }
        #pragma unroll
        for (int k = 0; k < PT_; k++){
            int i = tid + (k << 8);
            if (i < n){
                u64 v = cs[i];
                vv[k] = v;
                u64 ki = v & MAXK48;
                u32 r = 0;
                for (int j = 0; j < n; j += 8){
                    u64 c0 = cs[j+0]&MAXK48, c1 = cs[j+1]&MAXK48;
                    u64 c2 = cs[j+2]&MAXK48, c3 = cs[j+3]&MAXK48;
                    u64 c4 = cs[j+4]&MAXK48, c5 = cs[j+5]&MAXK48;
                    u64 c6 = cs[j+6]&MAXK48, c7 = cs[j+7]&MAXK48;
                    r += (u32)(c0<ki) + (u32)(c1<ki) + (u32)(c2<ki) + (u32)(c3<ki)
                       + (u32)(c4<ki) + (u32)(c5<ki) + (u32)(c6<ki) + (u32)(c7<ki);
                }
                rr[k] = r;
            }
        }
        __syncthreads();
        #pragma unroll
        for (int k = 0; k < PT_; k++){
            int i = tid + (k << 8);
            if (i < n) cs[rr[k]] = vv[k];
        }
        __syncthreads();
    }

    // ---- write sorted stream + count to global ----
    for (int i = tid; i < n; i += 256) candO[(size_t)b*MAXC_ + i] = cs[i];
    if (tid == 0) cntp[b] = n;
}

// ---------------- tail B: decode only (1 wave/block; LDS-resident stream) --------------------
__global__ __launch_bounds__(64) void k_tailB(const u64* __restrict__ candO,
                                              const int* __restrict__ cntp,
                                              float* __restrict__ outSel){
    __shared__ u64 cs[MAXC_];
    int b = blockIdx.x; int lane = threadIdx.x;
    int n = cntp[b];
    const u64* src = candO + (size_t)b*MAXC_;
    for (int i = lane; i < n; i += 64) cs[i] = src[i];
    __syncthreads();
    decode_wave(cs, n, outSel, b);
}

extern "C" void kernel_launch(void* const* d_in, const int* in_sizes, int n_in,
                              void* d_out, int out_size, void* d_ws, size_t ws_size,
                              hipStream_t stream){
    const float* hs        = (const float*)d_in[0];
    const float* ent_w1    = (const float*)d_in[1];
    const float* ent_b1    = (const float*)d_in[2];
    const float* ent_w2    = (const float*)d_in[3];
    const float* ent_b2    = (const float*)d_in[4];
    const float* span_w1   = (const float*)d_in[5];
    const float* span_b1   = (const float*)d_in[6];
    const float* span_w2   = (const float*)d_in[7];
    const float* span_b2   = (const float*)d_in[8];
    const int*  text_mask  = (const int*)d_in[9];
    const int*  ent_mask   = (const int*)d_in[10];
    const int*  word_index = (const int*)d_in[11];
    float* out = (float*)d_out;

    // ---- workspace (~24.8 MB peak; candS/candO overlay dead wemb) ----
    char* wsbase = (char*)d_ws; size_t off = 0;
    auto alloc = [&](size_t bytes)->void*{ void* p = wsbase + off; off = (off + bytes + 255) & ~(size_t)255; return p; };
    char*  region1 = (char*)alloc((size_t)B_*W_*H_*4);    // 12,386,304 B
    float* wemb   = (float*)region1;                       // phase 1
    u64*   candS  = (u64*)region1;                         // phase 2: 382,848 B
    u64*   candO  = (u64*)(region1 + 393216);              // 393,216 B (sorted streams)
    int*   tok    = (int*)  alloc((size_t)B_*W_*4*4);
    int*   tokc   = (int*)  alloc((size_t)B_*W_*4);
    float* PQ     = (float*)alloc((size_t)4*W_*1024*4);    // 8,257,536 B (4 batches/pass)
    float* logits = (float*)alloc((size_t)BNE_*4);         // 3,062,784 B
    int*   entpos = (int*)  alloc((size_t)B_*E_*4);
    float* hidg   = (float*)alloc((size_t)B_*E_*DFF_*4);   // 262,144 B
    float* entvec = (float*)alloc((size_t)B_*E_*H_*4);
    float* Mmat   = (float*)alloc((size_t)B_*DFF_*E_*4);
    float* cvec   = (float*)alloc((size_t)B_*E_*4);
    int*   starts = (int*)  alloc((size_t)N_*4);
    int*   ends   = (int*)  alloc((size_t)N_*4);
    int*   cntp   = (int*)  alloc((size_t)B_*4);

    k_prolog<<<9,256,0,stream>>>(ent_mask, entpos, starts, ends, tokc);
    k_toklist<<<(B_*L_+255)/256,256,0,stream>>>(text_mask, word_index, tok, tokc);
    k_poolsort<<<B_*W_,256,0,stream>>>(hs, tok, tokc, wemb);
    k_ent1<<<B_*E_*2,256,0,stream>>>(hs, entpos, ent_w1, ent_b1, hidg);
    k_ent2<<<B_*E_*3,256,0,stream>>>(hidg, ent_w2, ent_b2, entvec);
    k_Mc<<<257,256,0,stream>>>(span_w2, span_b2, entvec, Mmat, cvec);
    for (int b0 = 0; b0 < B_; b0 += 4){
        k_pq<<<512,256,0,stream>>>(wemb, span_w1, PQ, b0);
        k_logits<<<4*W_,256,0,stream>>>(PQ, Mmat, cvec, span_b1, logits, out, b0);
    }
    // wemb dead from here; region1 hosts candS/candO
    k_spanbest<<<(B_*N_+255)/256,256,0,stream>>>(logits, starts, ends, candS, out);
    k_tailA<<<B_,256,0,stream>>>(candS, candO, cntp);
    k_tailB<<<B_,64,0,stream>>>(candO, cntp, out);
}

// Round 11
// 418.279 us; speedup vs baseline: 1.0597x; 1.0260x over previous
//
#include <hip/hip_runtime.h>
#include <hip/hip_bf16.h>
#include <stdint.h>

#define B_ 8
#define L_ 1024
#define H_ 768
#define E_ 16
#define W_ 504
#define DFF_ 512
#define N_ 5982
#define NE_ (N_*E_)    // 95712 candidates per batch
#define BNE_ (B_*NE_)  // 765696
#define MAXK48 0x0000FFFFFFFFFFFFull
#define PT_ 24         // per-thread candidate slots (24*256 = 6144 >= N_)

typedef unsigned long long u64;
typedef unsigned int u32;

__device__ __forceinline__ int rowstart_of(int s){
    int s0 = W_ - 11; // 493
    if (s <= s0) return 12*s;
    int t = s - s0;
    return 12*s0 + t*11 - (t*(t-1))/2;
}

// ---------------- prolog: span tables + tokc zero (block 8), parallel entpos (blocks 0..7) ----
__global__ void k_prolog(const int* __restrict__ ent_mask, int* __restrict__ ent_pos,
                         int* __restrict__ starts, int* __restrict__ ends,
                         int* __restrict__ tokc){
    int blk = blockIdx.x; int tid = threadIdx.x;
    if (blk == 8){
        for (int s = tid; s < W_; s += 256){
            int rs = rowstart_of(s);
            int cnt = min(12, W_ - s);
            for (int i = 0; i < cnt; i++){ starts[rs+i] = s; ends[rs+i] = s+i; }
        }
        for (int i = tid; i < B_*W_; i += 256) tokc[i] = 0;
        return;
    }
    __shared__ u32 wt[4]; __shared__ u32 cbase;
    int b = blk;
    int lane = tid & 63, wave = tid >> 6;
    if (tid == 0) cbase = 0;
    __syncthreads();
    for (int base = 0; base < L_; base += 256){
        int l = base + tid;
        bool f = (ent_mask[b*L_ + l] == 1);
        u64 bal = __ballot(f);
        if (lane == 0) wt[wave] = (u32)__popcll(bal);
        __syncthreads();
        u32 pre = cbase;
        for (int w = 0; w < 4; w++) if (w < wave) pre += wt[w];
        if (f){
            u32 rank = pre + (u32)__popcll(bal & ((1ull<<lane)-1ull));
            if (rank < E_) ent_pos[b*E_ + rank] = l;
        }
        __syncthreads();
        if (tid == 0){ u32 r = cbase; for (int w = 0; w < 4; w++) r += wt[w]; cbase = r; }
        __syncthreads();
    }
    u32 totEnt = cbase;
    if (totEnt >= E_) return;                 // block-uniform
    for (int base = 0; base < L_; base += 256){
        int l = base + tid;
        bool f = (ent_mask[b*L_ + l] != 1);
        u64 bal = __ballot(f);
        if (lane == 0) wt[wave] = (u32)__popcll(bal);
        __syncthreads();
        u32 pre = cbase;
        for (int w = 0; w < 4; w++) if (w < wave) pre += wt[w];
        if (f){
            u32 rank = pre + (u32)__popcll(bal & ((1ull<<lane)-1ull));
            if (rank < E_) ent_pos[b*E_ + rank] = l;
        }
        __syncthreads();
        if (tid == 0){ u32 r = cbase; for (int w = 0; w < 4; w++) r += wt[w]; cbase = r; }
        __syncthreads();
    }
}

// ---------------- token lists: parallel build ----------------
__global__ void k_toklist(const int* __restrict__ tm, const int* __restrict__ wi,
                          int* __restrict__ tok, int* __restrict__ tokc){
    int i = blockIdx.x*256 + threadIdx.x;
    if (i >= B_*L_) return;
    int w = wi[i];
    if (tm[i] == 1 && w >= 0 && w < W_){
        int b = i / L_;
        int bw = b*W_ + w;
        int pos = atomicAdd(&tokc[bw], 1);
        if (pos < 4) tok[bw*4 + pos] = i - b*L_;
    }
}

// ---------------- fused per-word sort + mean pooling (one block per (b,w)) ----------------
__global__ void k_poolsort(const float* __restrict__ hs, const int* __restrict__ tok,
                           const int* __restrict__ tokc, float* __restrict__ wemb){
    __shared__ int stok[4]; __shared__ int scnt;
    int bw = blockIdx.x;                       // B_*W_
    int b = bw / W_;
    int tid = threadIdx.x;
    if (tid == 0){
        int c = tokc[bw]; int cc = min(c, 4);
        int v[4];
        for (int k = 0; k < cc; k++) v[k] = tok[bw*4 + k];
        for (int a = 1; a < cc; a++){ int x = v[a]; int j = a-1; while (j >= 0 && v[j] > x){ v[j+1] = v[j]; j--; } v[j+1] = x; }
        for (int k = 0; k < cc; k++) stok[k] = v[k];
        scnt = c;
    }
    __syncthreads();
    int c = scnt; int cc = min(c, 4);
    float denom = (float)max(c, 1);
    for (int h = tid; h < H_; h += 256){
        double s = 0.0;
        for (int k = 0; k < cc; k++)
            s += (double)hs[((size_t)(b*L_ + stok[k]))*H_ + h];
        wemb[(size_t)bw*H_ + h] = (float)(s / (double)denom);
    }
}

// ---------------- entity MLP layer 1 (one output/thread; deep load pipeline) ----------------
__global__ void k_ent1(const float* __restrict__ hs, const int* __restrict__ ent_pos,
                       const float* __restrict__ w1, const float* __restrict__ b1,
                       float* __restrict__ hidg){
    __shared__ float x[H_];
    int blk = blockIdx.x;            // 256 blocks: be*2 + half
    int be = blk >> 1; int half = blk & 1;
    int b = be >> 4;
    int tid = threadIdx.x;
    int pos = ent_pos[be];
    const float* xp = hs + ((size_t)b*L_ + pos)*H_;
    for (int j = tid; j < H_; j += 256) x[j] = xp[j];
    __syncthreads();
    int d = half*256 + tid;
    float a0=0.f,a1=0.f,a2=0.f,a3=0.f;
    const float* wp = w1 + d;
    #pragma unroll 8
    for (int h = 0; h < H_; h += 4){
        a0 += x[h+0]*wp[(size_t)(h+0)*DFF_];
        a1 += x[h+1]*wp[(size_t)(h+1)*DFF_];
        a2 += x[h+2]*wp[(size_t)(h+2)*DFF_];
        a3 += x[h+3]*wp[(size_t)(h+3)*DFF_];
    }
    float acc = ((a0+a1)+(a2+a3)) + b1[d];
    hidg[(size_t)be*DFF_ + d] = acc > 0.f ? acc : 0.01f*acc;
}

// ---------------- entity MLP layer 2 (one output/thread; deep load pipeline) ----------------
__global__ void k_ent2(const float* __restrict__ hidg,
                       const float* __restrict__ w2, const float* __restrict__ b2,
                       float* __restrict__ ent_vec){
    __shared__ float hsd[DFF_];
    int blk = blockIdx.x;            // 384 blocks: be*3 + third
    int be = blk / 3; int third = blk % 3;
    int tid = threadIdx.x;
    const float* hp = hidg + (size_t)be*DFF_;
    for (int j = tid; j < DFF_; j += 256) hsd[j] = hp[j];
    __syncthreads();
    int j = third*256 + tid;
    float a0=0.f,a1=0.f,a2=0.f,a3=0.f;
    const float* wp = w2 + j;
    #pragma unroll 8
    for (int d = 0; d < DFF_; d += 4){
        a0 += hsd[d+0]*wp[(size_t)(d+0)*H_];
        a1 += hsd[d+1]*wp[(size_t)(d+1)*H_];
        a2 += hsd[d+2]*wp[(size_t)(d+2)*H_];
        a3 += hsd[d+3]*wp[(size_t)(d+3)*H_];
    }
    ent_vec[(size_t)be*H_ + j] = ((a0+a1)+(a2+a3)) + b2[j];
}

// ---------------- fused M + c: blocks 0..255 = M, block 256 = c (fp64, decode-critical) ------
__global__ void k_Mc(const float* __restrict__ span_w2, const float* __restrict__ span_b2,
                     const float* __restrict__ ent_vec, float* __restrict__ M,
                     float* __restrict__ cvec){
    int blk = blockIdx.x;
    if (blk == 256){
        int i = threadIdx.x;
        if (i < B_*E_){
            const float* ev = ent_vec + (size_t)i*H_;
            double acc = 0.0;
            for (int h = 0; h < H_; h++) acc += (double)span_b2[h]*(double)ev[h];
            cvec[i] = (float)acc;
        }
        return;
    }
    int b = blk/32; int dbase = (blk%32)*16;
    int tid = threadIdx.x; int d = dbase + (tid>>4); int e = tid&15;
    const float* ev = ent_vec + ((size_t)b*E_ + e)*H_;
    const float* wr = span_w2 + (size_t)d*H_;
    double p0=0.0, p1=0.0;
    for (int h = 0; h < H_; h += 2){
        p0 += (double)wr[h]*(double)ev[h];
        p1 += (double)wr[h+1]*(double)ev[h+1];
    }
    M[((size_t)b*DFF_ + d)*E_ + e] = (float)(p0+p1);
}

// ---------------- P/Q projection: BK=32 + register-prefetch double buffering ----------------
__global__ void k_pq(const float* __restrict__ wemb, const float* __restrict__ w1,
                     float* __restrict__ PQ, int b0){
    __shared__ float As[32][68];
    __shared__ float Bs[32][68];
    int bx = blockIdx.x & 15;      // col tile
    int by = blockIdx.x >> 4;      // row tile (0..31)
    int tid = threadIdx.x;
    int tm = tid >> 4, tn = tid & 15;
    const float* A0 = wemb + (size_t)b0*W_*H_;
    int colbase = bx*64;
    const float* Bbase = (colbase < DFF_) ? w1 : (w1 + (size_t)H_*DFF_);
    int bcol0 = (colbase < DFF_) ? colbase : (colbase - DFF_);
    float acc[4][4] = {{0.f}};
    int ar = tid >> 2, akq = tid & 3;
    int bkk = tid >> 4, bcq = tid & 15;
    const int ROWS = 4*W_;         // 2016
    int gr = by*64 + ar;
    bool aok = (gr < ROWS);
    const float* Ap = A0 + (size_t)gr*H_ + akq*4;
    const float* Bp = Bbase + (size_t)bkk*DFF_ + bcol0 + bcq*4;
    float4 av0, av1, bv0, bv1;
    av0 = aok ? *(const float4*)(Ap + 0)  : make_float4(0.f,0.f,0.f,0.f);
    av1 = aok ? *(const float4*)(Ap + 16) : make_float4(0.f,0.f,0.f,0.f);
    bv0 = *(const float4*)(Bp + 0);
    bv1 = *(const float4*)(Bp + (size_t)16*DFF_);
    for (int k0 = 0; k0 < H_; k0 += 32){
        As[akq*4+0][ar] = av0.x; As[akq*4+1][ar] = av0.y;
        As[akq*4+2][ar] = av0.z; As[akq*4+3][ar] = av0.w;
        As[16+akq*4+0][ar] = av1.x; As[16+akq*4+1][ar] = av1.y;
        As[16+akq*4+2][ar] = av1.z; As[16+akq*4+3][ar] = av1.w;
        Bs[bkk][bcq*4+0] = bv0.x; Bs[bkk][bcq*4+1] = bv0.y;
        Bs[bkk][bcq*4+2] = bv0.z; Bs[bkk][bcq*4+3] = bv0.w;
        Bs[16+bkk][bcq*4+0] = bv1.x; Bs[16+bkk][bcq*4+1] = bv1.y;
        Bs[16+bkk][bcq*4+2] = bv1.z; Bs[16+bkk][bcq*4+3] = bv1.w;
        __syncthreads();
        if (k0 + 32 < H_){        // prefetch next chunk; latency hides under compute
            int kn = k0 + 32;
            av0 = aok ? *(const float4*)(Ap + kn)      : make_float4(0.f,0.f,0.f,0.f);
            av1 = aok ? *(const float4*)(Ap + kn + 16) : make_float4(0.f,0.f,0.f,0.f);
            bv0 = *(const float4*)(Bp + (size_t)kn*DFF_);
            bv1 = *(const float4*)(Bp + (size_t)(kn+16)*DFF_);
        }
        #pragma unroll
        for (int kk = 0; kk < 32; kk++){
            float4 a = *(const float4*)&As[kk][tm*4];
            float4 bv = *(const float4*)&Bs[kk][tn*4];
            acc[0][0] += a.x*bv.x; acc[0][1] += a.x*bv.y; acc[0][2] += a.x*bv.z; acc[0][3] += a.x*bv.w;
            acc[1][0] += a.y*bv.x; acc[1][1] += a.y*bv.y; acc[1][2] += a.y*bv.z; acc[1][3] += a.y*bv.w;
            acc[2][0] += a.z*bv.x; acc[2][1] += a.z*bv.y; acc[2][2] += a.z*bv.z; acc[2][3] += a.z*bv.w;
            acc[3][0] += a.w*bv.x; acc[3][1] += a.w*bv.y; acc[3][2] += a.w*bv.z; acc[3][3] += a.w*bv.w;
        }
        __syncthreads();
    }
    #pragma unroll
    for (int r = 0; r < 4; r++){
        int grr = by*64 + tm*4 + r;
        if (grr < ROWS){
            float4 ov = make_float4(acc[r][0], acc[r][1], acc[r][2], acc[r][3]);
            *(float4*)(PQ + (size_t)grr*1024 + colbase + tn*4) = ov;
        }
    }
}

// ---------------- logits: one block per (bl, s); 4-way fp64 accum + wave-shuffle reduce ------
__global__ void k_logits(const float* __restrict__ PQ, const float* __restrict__ Mmat,
                         const float* __restrict__ cvec, const float* __restrict__ span_b1,
                         float* __restrict__ logits, float* __restrict__ outL, int b0){
    __shared__ float Ps[DFF_];
    __shared__ float hid[DFF_];
    __shared__ double redw[64];
    __shared__ float csh[E_];
    int blk = blockIdx.x;            // 4*W_ blocks
    int bl = blk / W_; int s = blk - bl*W_;
    int b = b0 + bl;
    int tid = threadIdx.x;
    int lane = tid & 63, wave = tid >> 6;
    int ee = tid & 15; int g = tid >> 4;   // 16 groups x 32 d
    float Mreg[32];
    {
        const float* Mp = Mmat + (size_t)b*DFF_*E_ + (size_t)(g*32)*E_ + ee;
        #pragma unroll
        for (int i = 0; i < 32; i++) Mreg[i] = Mp[(size_t)i*E_];
    }
    const float* P = PQ + ((size_t)(bl*W_ + s))*1024;
    for (int d = tid; d < DFF_; d += 256) Ps[d] = P[d] + span_b1[d];
    if (tid < E_) csh[tid] = cvec[b*E_ + tid];
    __syncthreads();
    int nsp = min(12, W_ - s);
    int nbase = rowstart_of(s);
    for (int i = 0; i < nsp; i++){
        int e = s + i;
        const float* Q = PQ + ((size_t)(bl*W_ + e))*1024 + DFF_;
        for (int d = tid; d < DFF_; d += 256){
            float h = Ps[d] + Q[d];
            hid[d] = h > 0.f ? h : 0.01f*h;
        }
        __syncthreads();
        {
            int d0 = g*32;
            double a0=0.0, a1=0.0, a2=0.0, a3=0.0;   // 4 chains break the serial FMA dep
            #pragma unroll
            for (int k = 0; k < 32; k += 4){
                a0 += (double)hid[d0+k+0]*(double)Mreg[k+0];
                a1 += (double)hid[d0+k+1]*(double)Mreg[k+1];
                a2 += (double)hid[d0+k+2]*(double)Mreg[k+2];
                a3 += (double)hid[d0+k+3]*(double)Mreg[k+3];
            }
            double acc = (a0+a1)+(a2+a3);
            double t = acc + __shfl_down(acc, 32, 64);
            t = t + __shfl_down(t, 16, 64);
            if (lane < 16) redw[wave*16 + lane] = t;
        }
        __syncthreads();
        if (tid < E_){
            double t = ((redw[tid] + redw[16+tid]) + (redw[32+tid] + redw[48+tid]))
                     + (double)csh[tid];
            float lg = (float)t;
            size_t oi = ((size_t)b*N_ + nbase + i)*E_ + tid;
            logits[oi] = lg;
            outL[oi] = lg;
        }
        __syncthreads();
    }
}

// ---------------- per-span best candidate + selected-region zeroing ----------------
__global__ void k_spanbest(const float* __restrict__ logits,
                           const int* __restrict__ starts, const int* __restrict__ ends,
                           u64* __restrict__ candS, float* __restrict__ outSel){
    int idx = blockIdx.x*256 + threadIdx.x;      // over B_*N_
    if (idx >= B_*N_) return;
    int b = idx / N_; int n = idx - b*N_;
    const float* lg = logits + (size_t)b*NE_ + (size_t)n*16;
    u64 best = ~0ull;
    for (int e = 0; e < 16; e++){
        float prob = 1.0f/(1.0f + expf(-lg[e]));
        if (prob > 0.5f){
            u32 key24 = (~__float_as_uint(prob)) & 0xFFFFFFu;
            u64 pk = ((u64)key24 << 24) | (u64)(u32)(n*16 + e);
            best = best < pk ? best : pk;
        }
    }
    int s = starts[n], e2 = ends[n];
    int len = e2 - s + 1;
    u64 packed = best;
    if (best != ~0ull)
        packed = best | ((u64)(u32)s << 48) | ((u64)(u32)(len-1) << 57);
    candS[idx] = packed;
    float* selp = outSel + (size_t)BNE_ + (size_t)b*NE_ + (size_t)n*16;
    float4 z = make_float4(0.f,0.f,0.f,0.f);
    *(float4*)(selp+0)  = z; *(float4*)(selp+4)  = z;
    *(float4*)(selp+8)  = z; *(float4*)(selp+12) = z;
}

// ---------------- tail: priority-MIS fixpoint == exact greedy decode (one kernel) ------------
// Iterate: (1) mcov[w] = atomicMin over alive candidates covering w;
//          (2) accept candidates that are the min on EVERY word of their span ("clean"):
//              exact-greedy-accepted (all earlier-ranked overlappers already killed =
//              greedy-rejected => nothing covers their span at their turn);
//          (3) kill alive candidates overlapping an accepted one (greedy-rejected: the
//              accepted overlapper has a smaller key).
// Progress: the global-min alive candidate is always clean => terminates, exact.
// Accepted candidates are mutually disjoint (shared word => both can't be min there),
// so the coverage scatter is race-free. Replaces DP + compact + sort + decode.
__global__ __launch_bounds__(256) void k_tail(const u64* __restrict__ candS,
                                              float* __restrict__ outSel){
    __shared__ u64 cs[6144];     // 49,152 B candidate table
    __shared__ u64 mcov[512];    //  4,096 B per-word min key
    __shared__ u32 ckey[512];    //  2,048 B accepted-coverage flags
    int b = blockIdx.x; int tid = threadIdx.x;
    const u64* cSg = candS + (size_t)b*N_;
    u32 alive = 0;
    #pragma unroll
    for (int k = 0; k < PT_; k++){
        int i = tid + (k << 8);
        u64 v = (i < N_) ? cSg[i] : ~0ull;
        cs[i] = v;
        if (v != ~0ull) alive |= (1u << k);
    }
    // (first __syncthreads of the round loop fences the table writes)
    while (true){
        mcov[tid] = ~0ull; mcov[tid+256] = ~0ull;
        ckey[tid] = 0u;    ckey[tid+256] = 0u;
        __syncthreads();
        // scatter: per-word min key over alive candidates
        u32 am = alive;
        while (am){
            int k = __builtin_ctz(am); am &= am - 1u;
            u64 v = cs[tid + (k << 8)];
            int s   = (int)((v >> 48) & 0x1FFull);
            int len = (int)((v >> 57) & 0xFull) + 1;
            u64 key = v & MAXK48;
            for (int w = s; w < s + len; w++)
                atomicMin(&mcov[w], key);
        }
        __syncthreads();
        // gather: accept clean candidates; scatter their coverage
        u32 accm = 0;
        am = alive;
        while (am){
            int k = __builtin_ctz(am); am &= am - 1u;
            u64 v = cs[tid + (k << 8)];
            int s   = (int)((v >> 48) & 0x1FFull);
            int len = (int)((v >> 57) & 0xFull) + 1;
            u64 key = v & MAXK48;
            u64 rmin = ~0ull;
            for (int w = s; w < s + len; w++){ u64 t = mcov[w]; if (t < rmin) rmin = t; }
            if (rmin == key){
                accm |= (1u << k);
                for (int w = s; w < s + len; w++) ckey[w] = 1u;   // disjoint -> race-free
                u32 c = (u32)(v & 0xFFFFFFull);
                outSel[(size_t)BNE_ + (size_t)b*NE_ + (size_t)c] = 1.0f;
            }
        }
        alive &= ~accm;
        __syncthreads();
        // kill: alive candidates overlapping an accepted one
        u32 killm = 0;
        am = alive;
        while (am){
            int k = __builtin_ctz(am); am &= am - 1u;
            u64 v = cs[tid + (k << 8)];
            int s   = (int)((v >> 48) & 0x1FFull);
            int len = (int)((v >> 57) & 0xFull) + 1;
            u32 f = 0;
            for (int w = s; w < s + len; w++) f |= ckey[w];
            if (f) killm |= (1u << k);
        }
        alive &= ~killm;
        int na = __syncthreads_count(alive != 0u);
        if (na == 0) break;
    }
}

extern "C" void kernel_launch(void* const* d_in, const int* in_sizes, int n_in,
                              void* d_out, int out_size, void* d_ws, size_t ws_size,
                              hipStream_t stream){
    const float* hs        = (const float*)d_in[0];
    const float* ent_w1    = (const float*)d_in[1];
    const float* ent_b1    = (const float*)d_in[2];
    const float* ent_w2    = (const float*)d_in[3];
    const float* ent_b2    = (const float*)d_in[4];
    const float* span_w1   = (const float*)d_in[5];
    const float* span_b1   = (const float*)d_in[6];
    const float* span_w2   = (const float*)d_in[7];
    const float* span_b2   = (const float*)d_in[8];
    const int*  text_mask  = (const int*)d_in[9];
    const int*  ent_mask   = (const int*)d_in[10];
    const int*  word_index = (const int*)d_in[11];
    float* out = (float*)d_out;

    // ---- workspace (~24.8 MB peak; candS overlays dead wemb) ----
    char* wsbase = (char*)d_ws; size_t off = 0;
    auto alloc = [&](size_t bytes)->void*{ void* p = wsbase + off; off = (off + bytes + 255) & ~(size_t)255; return p; };
    char*  region1 = (char*)alloc((size_t)B_*W_*H_*4);    // 12,386,304 B
    float* wemb   = (float*)region1;                       // phase 1
    u64*   candS  = (u64*)region1;                         // phase 2: 382,848 B
    int*   tok    = (int*)  alloc((size_t)B_*W_*4*4);
    int*   tokc   = (int*)  alloc((size_t)B_*W_*4);
    float* PQ     = (float*)alloc((size_t)4*W_*1024*4);    // 8,257,536 B (4 batches/pass)
    float* logits = (float*)alloc((size_t)BNE_*4);         // 3,062,784 B
    int*   entpos = (int*)  alloc((size_t)B_*E_*4);
    float* hidg   = (float*)alloc((size_t)B_*E_*DFF_*4);   // 262,144 B
    float* entvec = (float*)alloc((size_t)B_*E_*H_*4);
    float* Mmat   = (float*)alloc((size_t)B_*DFF_*E_*4);
    float* cvec   = (float*)alloc((size_t)B_*E_*4);
    int*   starts = (int*)  alloc((size_t)N_*4);
    int*   ends   = (int*)  alloc((size_t)N_*4);

    k_prolog<<<9,256,0,stream>>>(ent_mask, entpos, starts, ends, tokc);
    k_toklist<<<(B_*L_+255)/256,256,0,stream>>>(text_mask, word_index, tok, tokc);
    k_poolsort<<<B_*W_,256,0,stream>>>(hs, tok, tokc, wemb);
    k_ent1<<<B_*E_*2,256,0,stream>>>(hs, entpos, ent_w1, ent_b1, hidg);
    k_ent2<<<B_*E_*3,256,0,stream>>>(hidg, ent_w2, ent_b2, entvec);
    k_Mc<<<257,256,0,stream>>>(span_w2, span_b2, entvec, Mmat, cvec);
    for (int b0 = 0; b0 < B_; b0 += 4){
        k_pq<<<512,256,0,stream>>>(wemb, span_w1, PQ, b0);
        k_logits<<<4*W_,256,0,stream>>>(PQ, Mmat, cvec, span_b1, logits, out, b0);
    }
    // wemb dead from here; region1 hosts candS
    k_spanbest<<<(B_*N_+255)/256,256,0,stream>>>(logits, starts, ends, candS, out);
    k_tail<<<B_,256,0,stream>>>(candS, out);
}